// Round 1
// baseline (1953.373 us; speedup 1.0000x reference)
//
#include <hip/hip_runtime.h>
#include <cstdint>
#include <cmath>

#define HID 96
#define INC 128
#define OUTC 40

// ---------------- threefry2x32 (JAX exact) ----------------
__device__ __forceinline__ unsigned rotl32d(unsigned x, int r){ return (x<<r)|(x>>(32-r)); }

__device__ __forceinline__ void tf2x32_dev(unsigned k0, unsigned k1, unsigned x0, unsigned x1,
                                           unsigned &y0, unsigned &y1){
  unsigned ks2 = k0 ^ k1 ^ 0x1BD11BDAu;
  x0 += k0; x1 += k1;
#define TFR(r) { x0 += x1; x1 = rotl32d(x1, r); x1 ^= x0; }
  TFR(13) TFR(15) TFR(26) TFR(6)   x0 += k1;  x1 += ks2 + 1u;
  TFR(17) TFR(29) TFR(16) TFR(24)  x0 += ks2; x1 += k0 + 2u;
  TFR(13) TFR(15) TFR(26) TFR(6)   x0 += k0;  x1 += k1 + 3u;
  TFR(17) TFR(29) TFR(16) TFR(24)  x0 += k1;  x1 += ks2 + 4u;
  TFR(13) TFR(15) TFR(26) TFR(6)   x0 += ks2; x1 += k0 + 5u;
#undef TFR
  y0 = x0; y1 = x1;
}

// Partitionable-mode 32-bit random bits for flat index idx (hi word of 64-bit iota == 0)
__device__ __forceinline__ unsigned tf_bits(unsigned k0, unsigned k1, unsigned idx){
  unsigned y0, y1; tf2x32_dev(k0, k1, 0u, idx, y0, y1); return y0 ^ y1;
}

__device__ __forceinline__ float u01_from_bits(unsigned bits){
  return __uint_as_float((bits >> 9) | 0x3f800000u) - 1.0f;
}

// XLA f32 ErfInv polynomial
__device__ __forceinline__ float erfinv_xla(float x){
  float w = -log1pf(-x*x);
  float p;
  if (w < 5.0f){
    w = w - 2.5f;
    p = 2.81022636e-08f;
    p = fmaf(p,w, 3.43273939e-07f);
    p = fmaf(p,w,-3.5233877e-06f);
    p = fmaf(p,w,-4.39150654e-06f);
    p = fmaf(p,w, 0.00021858087f);
    p = fmaf(p,w,-0.00125372503f);
    p = fmaf(p,w,-0.00417768164f);
    p = fmaf(p,w, 0.246640727f);
    p = fmaf(p,w, 1.50140941f);
  } else {
    w = sqrtf(w) - 3.0f;
    p = -0.000200214257f;
    p = fmaf(p,w, 0.000100950558f);
    p = fmaf(p,w, 0.00134934322f);
    p = fmaf(p,w,-0.00367342844f);
    p = fmaf(p,w, 0.00573950773f);
    p = fmaf(p,w,-0.0076224613f);
    p = fmaf(p,w, 0.00943887047f);
    p = fmaf(p,w, 1.00167406f);
    p = fmaf(p,w, 2.83297682f);
  }
  return p*x;
}

// ---------------- setup kernels ----------------
// Detect int64 vs int32 edge buffer: int64 => odd u32 words (high words) all zero.
__global__ void k_detect(const unsigned* __restrict__ raw, int* flag){
  unsigned v = raw[2*threadIdx.x + 1];
  unsigned long long m = __ballot(v == 0u);
  if (threadIdx.x == 0) *flag = (m == 0xFFFFFFFFFFFFFFFFull) ? 1 : 0;
}

__global__ void k_convert(const unsigned* __restrict__ raw, const int* __restrict__ flag,
                          int E, int* __restrict__ src, int* __restrict__ dst){
  int e = blockIdx.x*256 + threadIdx.x; if (e >= E) return;
  if (*flag){ src[e] = (int)raw[2*(size_t)e]; dst[e] = (int)raw[2*((size_t)E + e)]; }
  else      { const int* r = (const int*)raw; src[e] = r[e]; dst[e] = r[E + e]; }
}

__global__ void k_count(const int* __restrict__ dst, int E, int* __restrict__ cnt){
  int e = blockIdx.x*256 + threadIdx.x;
  if (e < E) atomicAdd(&cnt[dst[e]], 1);
}

// single-block exclusive scan + dis = rsqrt(deg) (deg = cnt+1 for self loop)
__global__ void k_scan(const int* __restrict__ cnt, int N, int* __restrict__ rowptr,
                       float* __restrict__ dis){
  __shared__ int sums[1024];
  int tid = threadIdx.x;
  int chunk = (N + 1023) / 1024;
  int lo = tid*chunk, hi = lo + chunk; if (hi > N) hi = N; if (lo > N) lo = N;
  int s = 0;
  for (int i = lo; i < hi; i++) s += cnt[i];
  sums[tid] = s; __syncthreads();
  for (int off = 1; off < 1024; off <<= 1){
    int v = (tid >= off) ? sums[tid - off] : 0;
    __syncthreads();
    sums[tid] += v;
    __syncthreads();
  }
  int prefix = (tid == 0) ? 0 : sums[tid-1];
  for (int i = lo; i < hi; i++){
    rowptr[i] = prefix;
    int c = cnt[i];
    prefix += c;
    dis[i] = 1.0f / sqrtf((float)(c + 1));
  }
  if (tid == 1023) rowptr[N] = sums[1023];
}

__global__ void k_fill(const int* __restrict__ src, const int* __restrict__ dst, int E,
                       const int* __restrict__ rowptr, int* __restrict__ cnt,
                       const float* __restrict__ dis,
                       int* __restrict__ csr_src, float* __restrict__ csr_w){
  int e = blockIdx.x*256 + threadIdx.x; if (e >= E) return;
  int d = dst[e], s = src[e];
  int pos = atomicAdd(&cnt[d], 1);
  int slot = rowptr[d] + pos;
  csr_src[slot] = s;
  csr_w[slot] = dis[s]*dis[d];
}

// ---------------- h0 = x@proj_w + b, plus layer-0 quantization (delta=1) ----------------
__global__ __launch_bounds__(256) void k_h0(
  const float* __restrict__ x, const float* __restrict__ W, const float* __restrict__ bias,
  float* __restrict__ h0, float* __restrict__ hq, unsigned kq0, unsigned kq1, int N)
{
  __shared__ float xs[64*65];     // 64 nodes x 64 K-chunk, pad 65
  __shared__ float wsh[64*96];    // K-chunk x 96
  int tid = threadIdx.x; int n0 = blockIdx.x*64;
  int cg = tid & 15, ng = tid >> 4; int c0 = cg*6;
  float acc[4][6];
#pragma unroll
  for (int i=0;i<4;i++) for (int j=0;j<6;j++) acc[i][j]=0.f;
  for (int kc=0; kc<2; kc++){
    if (kc) __syncthreads();
    for (int q=tid; q<1536; q+=256)
      ((float4*)wsh)[q] = ((const float4*)(W + kc*64*96))[q];
    for (int q=tid; q<1024; q+=256){
      int g=q*4; int r=g>>6, col=g&63;
      int n=n0+r; int ns = n<N ? n : N-1;
      float4 v = ((const float4*)(x + (size_t)ns*128 + kc*64))[col>>2];
      xs[r*65+col]=v.x; xs[r*65+col+1]=v.y; xs[r*65+col+2]=v.z; xs[r*65+col+3]=v.w;
    }
    __syncthreads();
    for (int k=0;k<64;k++){
      float wv[6];
#pragma unroll
      for (int j=0;j<6;j++) wv[j]=wsh[k*96 + c0 + j];
#pragma unroll
      for (int i=0;i<4;i++){
        float xv = xs[(ng*4+i)*65 + k];
#pragma unroll
        for (int j=0;j<6;j++) acc[i][j] = fmaf(xv, wv[j], acc[i][j]);
      }
    }
  }
#pragma unroll
  for (int i=0;i<4;i++){
    int n = n0 + ng*4 + i; if (n >= N) continue;
#pragma unroll
    for (int j=0;j<6;j++){
      int c = c0 + j; int p = n*96 + c;
      float v = acc[i][j] + bias[c];
      h0[p] = v;
      unsigned bq = tf_bits(kq0, kq1, (unsigned)p);
      float b = u01_from_bits(bq) - 0.5f;     // delta = 1
      hq[p] = floorf(v + b) - b;
    }
  }
}

// ---------------- CSR aggregation: t = 0.9*(sum hq[src]*norm + self) + 0.1*h0 ----------------
__global__ __launch_bounds__(192) void k_agg(
  const float* __restrict__ hq, const float* __restrict__ h0, const float* __restrict__ dis,
  const int* __restrict__ rowptr, const int* __restrict__ csr_src, const float* __restrict__ csr_w,
  float* __restrict__ tout, int N)
{
  int c = threadIdx.x;                      // 0..95
  int n = blockIdx.x*2 + threadIdx.y;
  if (n >= N) return;
  float d = dis[n];
  float acc = hq[(size_t)n*96 + c] * (d*d);  // self loop
  int lo = rowptr[n], hi = rowptr[n+1];
  for (int s = lo; s < hi; s++){
    int sn = csr_src[s];
    float w = csr_w[s];
    acc = fmaf(hq[(size_t)sn*96 + c], w, acc);
  }
  tout[(size_t)n*96 + c] = 0.9f*acc + 0.1f*h0[(size_t)n*96 + c];
}

// ---------------- M = t@W; h = (1-b)t + b*M; +noise; relu; dropout; next-layer quant ----------------
__global__ __launch_bounds__(256) void k_mmpost(
  const float* __restrict__ tbuf, const float* __restrict__ W,
  float betaf, float ombf,
  unsigned ke0, unsigned ke1, unsigned kd0, unsigned kd1,
  unsigned kq0, unsigned kq1, float delta_n, float invdelta_n,
  int do_dropout, int write_h,
  float* __restrict__ hq_out, float* __restrict__ h_out, int N)
{
  __shared__ float ts[64*97];
  __shared__ float wsh[96*96];
  int tid = threadIdx.x; int n0 = blockIdx.x*64;
  for (int q=tid; q<2304; q+=256)
    ((float4*)wsh)[q] = ((const float4*)W)[q];
  for (int q=tid; q<1536; q+=256){
    int g=q*4; int r=g/96, col=g%96;
    int n=n0+r; int ns = n<N ? n : N-1;
    float4 v = ((const float4*)(tbuf + (size_t)ns*96))[col>>2];
    ts[r*97+col]=v.x; ts[r*97+col+1]=v.y; ts[r*97+col+2]=v.z; ts[r*97+col+3]=v.w;
  }
  __syncthreads();
  int cg = tid & 15, ng = tid >> 4; int c0 = cg*6;
  float acc[4][6];
#pragma unroll
  for (int i=0;i<4;i++) for (int j=0;j<6;j++) acc[i][j]=0.f;
  for (int k=0;k<96;k++){
    float wv[6];
#pragma unroll
    for (int j=0;j<6;j++) wv[j]=wsh[k*96 + c0 + j];
#pragma unroll
    for (int i=0;i<4;i++){
      float xv = ts[(ng*4+i)*97 + k];
#pragma unroll
      for (int j=0;j<6;j++) acc[i][j] = fmaf(xv, wv[j], acc[i][j]);
    }
  }
  const float LO = __uint_as_float(0xBF7FFFFFu);   // nextafter(-1,0)
#pragma unroll
  for (int i=0;i<4;i++){
    int n = n0 + ng*4 + i; if (n >= N) continue;
#pragma unroll
    for (int j=0;j<6;j++){
      int c = c0 + j; int p = n*96 + c;
      float tv = ts[(ng*4+i)*97 + c];
      float hv = ombf*tv + betaf*acc[i][j];
      unsigned be = tf_bits(ke0, ke1, (unsigned)p);
      float uv = fmaxf(LO, u01_from_bits(be)*2.0f + LO);
      hv += 0.01f * (1.41421356f * erfinv_xla(uv));
      hv = fmaxf(hv, 0.0f);
      if (do_dropout){
        unsigned bd = tf_bits(kd0, kd1, (unsigned)p);
        hv = (bd < 0x80000000u) ? hv*2.0f : 0.0f;   // uniform<0.5 keep, /0.5
      }
      if (write_h){
        h_out[p] = hv;
      } else {
        unsigned bq = tf_bits(kq0, kq1, (unsigned)p);
        float b = (u01_from_bits(bq) - 0.5f)*delta_n;
        hq_out[p] = floorf((hv + b)*invdelta_n)*delta_n - b;
      }
    }
  }
}

// ---------------- out = [h0, h] @ out_w + out_b ----------------
__global__ __launch_bounds__(256) void k_final(
  const float* __restrict__ h0, const float* __restrict__ h,
  const float* __restrict__ W, const float* __restrict__ bias,
  float* __restrict__ out, int N)
{
  __shared__ float xs[64*97];
  __shared__ float wsh[96*40];
  int tid = threadIdx.x; int n0 = blockIdx.x*64;
  int cg = tid & 7, ng = tid >> 3; int c0 = cg*5;
  float acc[2][5];
#pragma unroll
  for (int i=0;i<2;i++) for (int j=0;j<5;j++) acc[i][j]=0.f;
  for (int ph=0; ph<2; ph++){
    if (ph) __syncthreads();
    const float* xsrc = ph ? h : h0;
    for (int q=tid; q<960; q+=256)
      ((float4*)wsh)[q] = ((const float4*)(W + ph*96*40))[q];
    for (int q=tid; q<1536; q+=256){
      int g=q*4; int r=g/96, col=g%96;
      int n=n0+r; int ns = n<N ? n : N-1;
      float4 v = ((const float4*)(xsrc + (size_t)ns*96))[col>>2];
      xs[r*97+col]=v.x; xs[r*97+col+1]=v.y; xs[r*97+col+2]=v.z; xs[r*97+col+3]=v.w;
    }
    __syncthreads();
    for (int k=0;k<96;k++){
      float wv[5];
#pragma unroll
      for (int j=0;j<5;j++) wv[j]=wsh[k*40 + c0 + j];
#pragma unroll
      for (int i=0;i<2;i++){
        float xv = xs[(ng*2+i)*97 + k];
#pragma unroll
        for (int j=0;j<5;j++) acc[i][j] = fmaf(xv, wv[j], acc[i][j]);
      }
    }
  }
#pragma unroll
  for (int i=0;i<2;i++){
    int n = n0 + ng*2 + i; if (n >= N) continue;
#pragma unroll
    for (int j=0;j<5;j++)
      out[(size_t)n*40 + c0 + j] = acc[i][j] + bias[c0 + j];
  }
}

// ---------------- host ----------------
static void tf_host(uint32_t k0, uint32_t k1, uint32_t x0, uint32_t x1,
                    uint32_t &y0, uint32_t &y1){
  uint32_t ks2 = k0 ^ k1 ^ 0x1BD11BDAu;
  x0 += k0; x1 += k1;
  auto R = [&](int r){ x0 += x1; x1 = (x1<<r)|(x1>>(32-r)); x1 ^= x0; };
  R(13);R(15);R(26);R(6);   x0 += k1;  x1 += ks2 + 1u;
  R(17);R(29);R(16);R(24);  x0 += ks2; x1 += k0 + 2u;
  R(13);R(15);R(26);R(6);   x0 += k0;  x1 += k1 + 3u;
  R(17);R(29);R(16);R(24);  x0 += k1;  x1 += ks2 + 4u;
  R(13);R(15);R(26);R(6);   x0 += ks2; x1 += k0 + 5u;
  y0 = x0; y1 = x1;
}

extern "C" void kernel_launch(void* const* d_in, const int* in_sizes, int n_in,
                              void* d_out, int out_size, void* d_ws, size_t ws_size,
                              hipStream_t stream)
{
  const float*    x       = (const float*)d_in[0];
  const unsigned* eraw    = (const unsigned*)d_in[1];
  const float*    proj_w  = (const float*)d_in[2];
  const float*    proj_b  = (const float*)d_in[3];
  const float*    conv_w  = (const float*)d_in[4];
  const float*    out_w   = (const float*)d_in[5];
  const float*    out_b   = (const float*)d_in[6];
  float* out = (float*)d_out;

  const int N = in_sizes[0] / INC;     // 50000
  const int E = in_sizes[1] / 2;       // 800000
  const size_t NH = (size_t)N * HID;

  float* ws     = (float*)d_ws;
  float* h0     = ws;
  float* hq     = h0 + NH;
  float* tb     = hq + NH;
  float* hb     = tb + NH;
  float* dis    = hb + NH;
  int*   cnt    = (int*)(dis + N);
  int*   rowptr = cnt + N;
  int*   csr_src= rowptr + (N + 1);
  float* csr_w  = (float*)(csr_src + E);
  int*   srcb   = (int*)(csr_w + E);
  int*   dstb   = srcb + E;
  int*   flag   = dstb + E;
  (void)ws_size; (void)n_in; (void)out_size;

  // JAX key chain: key(42) -> per layer split(key,4) (partitionable foldlike)
  uint32_t kq[8][2], ke[8][2], kd[8][2];
  {
    uint32_t K0 = 0u, K1 = 42u;
    for (int k = 0; k < 8; k++){
      uint32_t y0, y1;
      tf_host(K0, K1, 0u, 0u, y0, y1); kq[k][0]=y0; kq[k][1]=y1;
      tf_host(K0, K1, 0u, 1u, y0, y1); ke[k][0]=y0; ke[k][1]=y1;
      tf_host(K0, K1, 0u, 2u, y0, y1); kd[k][0]=y0; kd[k][1]=y1;
      tf_host(K0, K1, 0u, 3u, y0, y1); K0=y0; K1=y1;
    }
  }

  const int gE  = (E + 255)/256;
  const int gMM = (N + 63)/64;

  hipMemsetAsync(cnt, 0, (size_t)N*4, stream);
  k_detect <<<1, 64, 0, stream>>>(eraw, flag);
  k_convert<<<gE, 256, 0, stream>>>(eraw, flag, E, srcb, dstb);
  k_count  <<<gE, 256, 0, stream>>>(dstb, E, cnt);
  k_scan   <<<1, 1024, 0, stream>>>(cnt, N, rowptr, dis);
  hipMemsetAsync(cnt, 0, (size_t)N*4, stream);
  k_fill   <<<gE, 256, 0, stream>>>(srcb, dstb, E, rowptr, cnt, dis, csr_src, csr_w);

  k_h0<<<gMM, 256, 0, stream>>>(x, proj_w, proj_b, h0, hq, kq[0][0], kq[0][1], N);

  for (int k = 0; k < 8; k++){
    k_agg<<<(N+1)/2, dim3(96,2), 0, stream>>>(hq, h0, dis, rowptr, csr_src, csr_w, tb, N);
    double bd = log(0.5/(double)(k+1) + 1.0);
    float betaf = (float)bd;
    float ombf  = (float)(1.0 - bd);
    int last = (k == 7);
    float dn  = 1.0f/(float)(1 << (k+1));
    float idn = (float)(1 << (k+1));
    k_mmpost<<<gMM, 256, 0, stream>>>(tb, conv_w + (size_t)k*HID*HID, betaf, ombf,
      ke[k][0], ke[k][1], kd[k][0], kd[k][1],
      last?0u:kq[k+1][0], last?0u:kq[k+1][1], dn, idn,
      !last, last, hq, hb, N);
  }

  k_final<<<gMM, 256, 0, stream>>>(h0, hb, out_w, out_b, out, N);
}

// Round 2
// 1844.872 us; speedup vs baseline: 1.0588x; 1.0588x over previous
//
#include <hip/hip_runtime.h>
#include <cstdint>
#include <cmath>

#define HID 96
#define INC 128
#define OUTC 40

// ---------------- threefry2x32 (JAX exact) ----------------
__device__ __forceinline__ unsigned rotl32d(unsigned x, int r){ return (x<<r)|(x>>(32-r)); }

__device__ __forceinline__ void tf2x32_dev(unsigned k0, unsigned k1, unsigned x0, unsigned x1,
                                           unsigned &y0, unsigned &y1){
  unsigned ks2 = k0 ^ k1 ^ 0x1BD11BDAu;
  x0 += k0; x1 += k1;
#define TFR(r) { x0 += x1; x1 = rotl32d(x1, r); x1 ^= x0; }
  TFR(13) TFR(15) TFR(26) TFR(6)   x0 += k1;  x1 += ks2 + 1u;
  TFR(17) TFR(29) TFR(16) TFR(24)  x0 += ks2; x1 += k0 + 2u;
  TFR(13) TFR(15) TFR(26) TFR(6)   x0 += k0;  x1 += k1 + 3u;
  TFR(17) TFR(29) TFR(16) TFR(24)  x0 += k1;  x1 += ks2 + 4u;
  TFR(13) TFR(15) TFR(26) TFR(6)   x0 += ks2; x1 += k0 + 5u;
#undef TFR
  y0 = x0; y1 = x1;
}

// Partitionable-mode 32-bit random bits for flat index idx (hi word of 64-bit iota == 0)
__device__ __forceinline__ unsigned tf_bits(unsigned k0, unsigned k1, unsigned idx){
  unsigned y0, y1; tf2x32_dev(k0, k1, 0u, idx, y0, y1); return y0 ^ y1;
}

__device__ __forceinline__ float u01_from_bits(unsigned bits){
  return __uint_as_float((bits >> 9) | 0x3f800000u) - 1.0f;
}

// XLA f32 ErfInv polynomial
__device__ __forceinline__ float erfinv_xla(float x){
  float w = -log1pf(-x*x);
  float p;
  if (w < 5.0f){
    w = w - 2.5f;
    p = 2.81022636e-08f;
    p = fmaf(p,w, 3.43273939e-07f);
    p = fmaf(p,w,-3.5233877e-06f);
    p = fmaf(p,w,-4.39150654e-06f);
    p = fmaf(p,w, 0.00021858087f);
    p = fmaf(p,w,-0.00125372503f);
    p = fmaf(p,w,-0.00417768164f);
    p = fmaf(p,w, 0.246640727f);
    p = fmaf(p,w, 1.50140941f);
  } else {
    w = sqrtf(w) - 3.0f;
    p = -0.000200214257f;
    p = fmaf(p,w, 0.000100950558f);
    p = fmaf(p,w, 0.00134934322f);
    p = fmaf(p,w,-0.00367342844f);
    p = fmaf(p,w, 0.00573950773f);
    p = fmaf(p,w,-0.0076224613f);
    p = fmaf(p,w, 0.00943887047f);
    p = fmaf(p,w, 1.00167406f);
    p = fmaf(p,w, 2.83297682f);
  }
  return p*x;
}

// ---------------- setup kernels ----------------
// Detect int64 vs int32 edge buffer: int64 => odd u32 words (high words) all zero.
__global__ void k_detect(const unsigned* __restrict__ raw, int* flag){
  unsigned v = raw[2*threadIdx.x + 1];
  unsigned long long m = __ballot(v == 0u);
  if (threadIdx.x == 0) *flag = (m == 0xFFFFFFFFFFFFFFFFull) ? 1 : 0;
}

__global__ void k_convert(const unsigned* __restrict__ raw, const int* __restrict__ flag,
                          int E, int* __restrict__ src, int* __restrict__ dst){
  int e = blockIdx.x*256 + threadIdx.x; if (e >= E) return;
  if (*flag){ src[e] = (int)raw[2*(size_t)e]; dst[e] = (int)raw[2*((size_t)E + e)]; }
  else      { const int* r = (const int*)raw; src[e] = r[e]; dst[e] = r[E + e]; }
}

__global__ void k_count(const int* __restrict__ dst, int E, int* __restrict__ cnt){
  int e = blockIdx.x*256 + threadIdx.x;
  if (e < E) atomicAdd(&cnt[dst[e]], 1);
}

// single-block exclusive scan + dis = rsqrt(deg) (deg = cnt+1 for self loop)
__global__ void k_scan(const int* __restrict__ cnt, int N, int* __restrict__ rowptr,
                       float* __restrict__ dis){
  __shared__ int sums[1024];
  int tid = threadIdx.x;
  int chunk = (N + 1023) / 1024;
  int lo = tid*chunk, hi = lo + chunk; if (hi > N) hi = N; if (lo > N) lo = N;
  int s = 0;
  for (int i = lo; i < hi; i++) s += cnt[i];
  sums[tid] = s; __syncthreads();
  for (int off = 1; off < 1024; off <<= 1){
    int v = (tid >= off) ? sums[tid - off] : 0;
    __syncthreads();
    sums[tid] += v;
    __syncthreads();
  }
  int prefix = (tid == 0) ? 0 : sums[tid-1];
  for (int i = lo; i < hi; i++){
    rowptr[i] = prefix;
    int c = cnt[i];
    prefix += c;
    dis[i] = 1.0f / sqrtf((float)(c + 1));
  }
  if (tid == 1023) rowptr[N] = sums[1023];
}

__global__ void k_fill(const int* __restrict__ src, const int* __restrict__ dst, int E,
                       const int* __restrict__ rowptr, int* __restrict__ cnt,
                       const float* __restrict__ dis,
                       int* __restrict__ csr_src, float* __restrict__ csr_w){
  int e = blockIdx.x*256 + threadIdx.x; if (e >= E) return;
  int d = dst[e], s = src[e];
  int pos = atomicAdd(&cnt[d], 1);
  int slot = rowptr[d] + pos;
  csr_src[slot] = s;
  csr_w[slot] = dis[s]*dis[d];
}

// ---------------- h0 = x@proj_w + b, plus layer-0 quantization (delta=1) ----------------
__global__ __launch_bounds__(256) void k_h0(
  const float* __restrict__ x, const float* __restrict__ W, const float* __restrict__ bias,
  float* __restrict__ h0, float* __restrict__ hq, unsigned kq0, unsigned kq1, int N)
{
  __shared__ float xs[64*65];     // 64 nodes x 64 K-chunk, pad 65
  __shared__ float wsh[64*96];    // K-chunk x 96
  int tid = threadIdx.x; int n0 = blockIdx.x*64;
  int cg = tid & 15, ng = tid >> 4; int c0 = cg*6;
  float acc[4][6];
#pragma unroll
  for (int i=0;i<4;i++) for (int j=0;j<6;j++) acc[i][j]=0.f;
  for (int kc=0; kc<2; kc++){
    if (kc) __syncthreads();
    for (int q=tid; q<1536; q+=256)
      ((float4*)wsh)[q] = ((const float4*)(W + kc*64*96))[q];
    for (int q=tid; q<1024; q+=256){
      int g=q*4; int r=g>>6, col=g&63;
      int n=n0+r; int ns = n<N ? n : N-1;
      float4 v = ((const float4*)(x + (size_t)ns*128 + kc*64))[col>>2];
      xs[r*65+col]=v.x; xs[r*65+col+1]=v.y; xs[r*65+col+2]=v.z; xs[r*65+col+3]=v.w;
    }
    __syncthreads();
    for (int k=0;k<64;k++){
      float wv[6];
#pragma unroll
      for (int j=0;j<6;j++) wv[j]=wsh[k*96 + c0 + j];
#pragma unroll
      for (int i=0;i<4;i++){
        float xv = xs[(ng*4+i)*65 + k];
#pragma unroll
        for (int j=0;j<6;j++) acc[i][j] = fmaf(xv, wv[j], acc[i][j]);
      }
    }
  }
#pragma unroll
  for (int i=0;i<4;i++){
    int n = n0 + ng*4 + i; if (n >= N) continue;
#pragma unroll
    for (int j=0;j<6;j++){
      int c = c0 + j; int p = n*96 + c;
      float v = acc[i][j] + bias[c];
      h0[p] = v;
      unsigned bq = tf_bits(kq0, kq1, (unsigned)p);
      float b = u01_from_bits(bq) - 0.5f;     // delta = 1
      hq[p] = floorf(v + b) - b;
    }
  }
}

// ---------------- CSR aggregation: t = 0.9*(sum hq[src]*norm + self) + 0.1*h0 ----------------
__global__ __launch_bounds__(192) void k_agg(
  const float* __restrict__ hq, const float* __restrict__ h0, const float* __restrict__ dis,
  const int* __restrict__ rowptr, const int* __restrict__ csr_src, const float* __restrict__ csr_w,
  float* __restrict__ tout, int N)
{
  int c = threadIdx.x;                      // 0..95
  int n = blockIdx.x*2 + threadIdx.y;
  if (n >= N) return;
  float d = dis[n];
  float acc = hq[(size_t)n*96 + c] * (d*d);  // self loop
  int lo = rowptr[n], hi = rowptr[n+1];
  for (int s = lo; s < hi; s++){
    int sn = csr_src[s];
    float w = csr_w[s];
    acc = fmaf(hq[(size_t)sn*96 + c], w, acc);
  }
  tout[(size_t)n*96 + c] = 0.9f*acc + 0.1f*h0[(size_t)n*96 + c];
}

// ---------------- M = t@W; h = (1-b)t + b*M; +noise; relu; dropout; next-layer quant ----------------
// Round 1 restructure: 8 col-groups (12 cols, 3x ds_read_b128, conflict-free bank-quads
// 12*cg mod 32 = {0,12,24,4,16,28,8,20}) x 32 node-groups x 2 nodes.
// W staged in two 48-row K-chunks -> LDS 44032 B -> 3 blocks/CU (was 61952 B -> 2).
__global__ __launch_bounds__(256, 3) void k_mmpost(
  const float* __restrict__ tbuf, const float* __restrict__ W,
  float betaf, float ombf,
  unsigned ke0, unsigned ke1, unsigned kd0, unsigned kd1,
  unsigned kq0, unsigned kq1, float delta_n, float invdelta_n,
  int do_dropout, int write_h,
  float* __restrict__ hq_out, float* __restrict__ h_out, int N)
{
  __shared__ float ts[64*100];   // 25600 B, stride 100 (b128-aligned, 2-way-free banks)
  __shared__ float wsh[48*96];   // 18432 B, K-chunk, row-major
  int tid = threadIdx.x; int n0 = blockIdx.x*64;

  // stage t tile: 64 rows x 96 cols = 1536 float4
  for (int q = tid; q < 1536; q += 256){
    int r = q / 24, c4 = (q % 24) * 4;
    int n = n0 + r; int ns = n < N ? n : N - 1;
    float4 v = ((const float4*)(tbuf + (size_t)ns*96))[c4 >> 2];
    *((float4*)&ts[r*100 + c4]) = v;
  }

  int cg = tid & 7, ng = tid >> 3;   // cg 0..7, ng 0..31
  int c0 = cg * 12;
  int r0 = ng * 2;
  float acc[2][12];
#pragma unroll
  for (int i = 0; i < 2; i++)
#pragma unroll
    for (int j = 0; j < 12; j++) acc[i][j] = 0.f;

  for (int chunk = 0; chunk < 2; chunk++){
    __syncthreads();   // first: ts staged; later: previous chunk consumed
    for (int q = tid; q < 1152; q += 256)
      ((float4*)wsh)[q] = ((const float4*)(W + chunk*48*96))[q];
    __syncthreads();
#pragma unroll 4
    for (int kk = 0; kk < 48; kk++){
      int k = chunk*48 + kk;
      float4 w0 = *((const float4*)&wsh[kk*96 + c0]);
      float4 w1 = *((const float4*)&wsh[kk*96 + c0 + 4]);
      float4 w2 = *((const float4*)&wsh[kk*96 + c0 + 8]);
      float xv0 = ts[r0*100 + k];
      float xv1 = ts[(r0+1)*100 + k];
      acc[0][0] = fmaf(xv0, w0.x, acc[0][0]);  acc[0][1] = fmaf(xv0, w0.y, acc[0][1]);
      acc[0][2] = fmaf(xv0, w0.z, acc[0][2]);  acc[0][3] = fmaf(xv0, w0.w, acc[0][3]);
      acc[0][4] = fmaf(xv0, w1.x, acc[0][4]);  acc[0][5] = fmaf(xv0, w1.y, acc[0][5]);
      acc[0][6] = fmaf(xv0, w1.z, acc[0][6]);  acc[0][7] = fmaf(xv0, w1.w, acc[0][7]);
      acc[0][8] = fmaf(xv0, w2.x, acc[0][8]);  acc[0][9] = fmaf(xv0, w2.y, acc[0][9]);
      acc[0][10]= fmaf(xv0, w2.z, acc[0][10]); acc[0][11]= fmaf(xv0, w2.w, acc[0][11]);
      acc[1][0] = fmaf(xv1, w0.x, acc[1][0]);  acc[1][1] = fmaf(xv1, w0.y, acc[1][1]);
      acc[1][2] = fmaf(xv1, w0.z, acc[1][2]);  acc[1][3] = fmaf(xv1, w0.w, acc[1][3]);
      acc[1][4] = fmaf(xv1, w1.x, acc[1][4]);  acc[1][5] = fmaf(xv1, w1.y, acc[1][5]);
      acc[1][6] = fmaf(xv1, w1.z, acc[1][6]);  acc[1][7] = fmaf(xv1, w1.w, acc[1][7]);
      acc[1][8] = fmaf(xv1, w2.x, acc[1][8]);  acc[1][9] = fmaf(xv1, w2.y, acc[1][9]);
      acc[1][10]= fmaf(xv1, w2.z, acc[1][10]); acc[1][11]= fmaf(xv1, w2.w, acc[1][11]);
    }
  }

  const float LO = __uint_as_float(0xBF7FFFFFu);   // nextafter(-1,0)
#pragma unroll
  for (int i = 0; i < 2; i++){
    int n = n0 + r0 + i; if (n >= N) continue;
    float res[12];
#pragma unroll
    for (int j = 0; j < 12; j++){
      int c = c0 + j; int p = n*96 + c;
      float tv = ts[(r0+i)*100 + c];
      float hv = ombf*tv + betaf*acc[i][j];
      unsigned be = tf_bits(ke0, ke1, (unsigned)p);
      float uv = fmaxf(LO, u01_from_bits(be)*2.0f + LO);
      hv += 0.01f * (1.41421356f * erfinv_xla(uv));
      hv = fmaxf(hv, 0.0f);
      if (do_dropout){
        unsigned bd = tf_bits(kd0, kd1, (unsigned)p);
        hv = (bd < 0x80000000u) ? hv*2.0f : 0.0f;   // uniform<0.5 keep, /0.5
      }
      if (!write_h){
        unsigned bq = tf_bits(kq0, kq1, (unsigned)p);
        float b = (u01_from_bits(bq) - 0.5f)*delta_n;
        hv = floorf((hv + b)*invdelta_n)*delta_n - b;
      }
      res[j] = hv;
    }
    float* dst = (write_h ? h_out : hq_out) + (size_t)n*96 + c0;
#pragma unroll
    for (int j4 = 0; j4 < 3; j4++)
      *((float4*)&dst[j4*4]) = make_float4(res[j4*4], res[j4*4+1], res[j4*4+2], res[j4*4+3]);
  }
}

// ---------------- out = [h0, h] @ out_w + out_b ----------------
__global__ __launch_bounds__(256) void k_final(
  const float* __restrict__ h0, const float* __restrict__ h,
  const float* __restrict__ W, const float* __restrict__ bias,
  float* __restrict__ out, int N)
{
  __shared__ float xs[64*97];
  __shared__ float wsh[96*40];
  int tid = threadIdx.x; int n0 = blockIdx.x*64;
  int cg = tid & 7, ng = tid >> 3; int c0 = cg*5;
  float acc[2][5];
#pragma unroll
  for (int i=0;i<2;i++) for (int j=0;j<5;j++) acc[i][j]=0.f;
  for (int ph=0; ph<2; ph++){
    if (ph) __syncthreads();
    const float* xsrc = ph ? h : h0;
    for (int q=tid; q<960; q+=256)
      ((float4*)wsh)[q] = ((const float4*)(W + ph*96*40))[q];
    for (int q=tid; q<1536; q+=256){
      int g=q*4; int r=g/96, col=g%96;
      int n=n0+r; int ns = n<N ? n : N-1;
      float4 v = ((const float4*)(xsrc + (size_t)ns*96))[col>>2];
      xs[r*97+col]=v.x; xs[r*97+col+1]=v.y; xs[r*97+col+2]=v.z; xs[r*97+col+3]=v.w;
    }
    __syncthreads();
    for (int k=0;k<96;k++){
      float wv[5];
#pragma unroll
      for (int j=0;j<5;j++) wv[j]=wsh[k*40 + c0 + j];
#pragma unroll
      for (int i=0;i<2;i++){
        float xv = xs[(ng*2+i)*97 + k];
#pragma unroll
        for (int j=0;j<5;j++) acc[i][j] = fmaf(xv, wv[j], acc[i][j]);
      }
    }
  }
#pragma unroll
  for (int i=0;i<2;i++){
    int n = n0 + ng*2 + i; if (n >= N) continue;
#pragma unroll
    for (int j=0;j<5;j++)
      out[(size_t)n*40 + c0 + j] = acc[i][j] + bias[c0 + j];
  }
}

// ---------------- host ----------------
static void tf_host(uint32_t k0, uint32_t k1, uint32_t x0, uint32_t x1,
                    uint32_t &y0, uint32_t &y1){
  uint32_t ks2 = k0 ^ k1 ^ 0x1BD11BDAu;
  x0 += k0; x1 += k1;
  auto R = [&](int r){ x0 += x1; x1 = (x1<<r)|(x1>>(32-r)); x1 ^= x0; };
  R(13);R(15);R(26);R(6);   x0 += k1;  x1 += ks2 + 1u;
  R(17);R(29);R(16);R(24);  x0 += ks2; x1 += k0 + 2u;
  R(13);R(15);R(26);R(6);   x0 += k0;  x1 += k1 + 3u;
  R(17);R(29);R(16);R(24);  x0 += k1;  x1 += ks2 + 4u;
  R(13);R(15);R(26);R(6);   x0 += ks2; x1 += k0 + 5u;
  y0 = x0; y1 = x1;
}

extern "C" void kernel_launch(void* const* d_in, const int* in_sizes, int n_in,
                              void* d_out, int out_size, void* d_ws, size_t ws_size,
                              hipStream_t stream)
{
  const float*    x       = (const float*)d_in[0];
  const unsigned* eraw    = (const unsigned*)d_in[1];
  const float*    proj_w  = (const float*)d_in[2];
  const float*    proj_b  = (const float*)d_in[3];
  const float*    conv_w  = (const float*)d_in[4];
  const float*    out_w   = (const float*)d_in[5];
  const float*    out_b   = (const float*)d_in[6];
  float* out = (float*)d_out;

  const int N = in_sizes[0] / INC;     // 50000
  const int E = in_sizes[1] / 2;       // 800000
  const size_t NH = (size_t)N * HID;

  float* ws     = (float*)d_ws;
  float* h0     = ws;
  float* hq     = h0 + NH;
  float* tb     = hq + NH;
  float* hb     = tb + NH;
  float* dis    = hb + NH;
  int*   cnt    = (int*)(dis + N);
  int*   rowptr = cnt + N;
  int*   csr_src= rowptr + (N + 1);
  float* csr_w  = (float*)(csr_src + E);
  int*   srcb   = (int*)(csr_w + E);
  int*   dstb   = srcb + E;
  int*   flag   = dstb + E;
  (void)ws_size; (void)n_in; (void)out_size;

  // JAX key chain: key(42) -> per layer split(key,4) (partitionable foldlike)
  uint32_t kq[8][2], ke[8][2], kd[8][2];
  {
    uint32_t K0 = 0u, K1 = 42u;
    for (int k = 0; k < 8; k++){
      uint32_t y0, y1;
      tf_host(K0, K1, 0u, 0u, y0, y1); kq[k][0]=y0; kq[k][1]=y1;
      tf_host(K0, K1, 0u, 1u, y0, y1); ke[k][0]=y0; ke[k][1]=y1;
      tf_host(K0, K1, 0u, 2u, y0, y1); kd[k][0]=y0; kd[k][1]=y1;
      tf_host(K0, K1, 0u, 3u, y0, y1); K0=y0; K1=y1;
    }
  }

  const int gE  = (E + 255)/256;
  const int gMM = (N + 63)/64;

  hipMemsetAsync(cnt, 0, (size_t)N*4, stream);
  k_detect <<<1, 64, 0, stream>>>(eraw, flag);
  k_convert<<<gE, 256, 0, stream>>>(eraw, flag, E, srcb, dstb);
  k_count  <<<gE, 256, 0, stream>>>(dstb, E, cnt);
  k_scan   <<<1, 1024, 0, stream>>>(cnt, N, rowptr, dis);
  hipMemsetAsync(cnt, 0, (size_t)N*4, stream);
  k_fill   <<<gE, 256, 0, stream>>>(srcb, dstb, E, rowptr, cnt, dis, csr_src, csr_w);

  k_h0<<<gMM, 256, 0, stream>>>(x, proj_w, proj_b, h0, hq, kq[0][0], kq[0][1], N);

  for (int k = 0; k < 8; k++){
    k_agg<<<(N+1)/2, dim3(96,2), 0, stream>>>(hq, h0, dis, rowptr, csr_src, csr_w, tb, N);
    double bd = log(0.5/(double)(k+1) + 1.0);
    float betaf = (float)bd;
    float ombf  = (float)(1.0 - bd);
    int last = (k == 7);
    float dn  = 1.0f/(float)(1 << (k+1));
    float idn = (float)(1 << (k+1));
    k_mmpost<<<gMM, 256, 0, stream>>>(tb, conv_w + (size_t)k*HID*HID, betaf, ombf,
      ke[k][0], ke[k][1], kd[k][0], kd[k][1],
      last?0u:kq[k+1][0], last?0u:kq[k+1][1], dn, idn,
      !last, last, hq, hb, N);
  }

  k_final<<<gMM, 256, 0, stream>>>(h0, hb, out_w, out_b, out, N);
}

// Round 3
// 1598.956 us; speedup vs baseline: 1.2217x; 1.1538x over previous
//
#include <hip/hip_runtime.h>
#include <cstdint>
#include <cmath>

#define HID 96
#define INC 128
#define OUTC 40

// ---------------- threefry2x32 (JAX exact) ----------------
__device__ __forceinline__ unsigned rotl32d(unsigned x, int r){ return (x<<r)|(x>>(32-r)); }

__device__ __forceinline__ void tf2x32_dev(unsigned k0, unsigned k1, unsigned x0, unsigned x1,
                                           unsigned &y0, unsigned &y1){
  unsigned ks2 = k0 ^ k1 ^ 0x1BD11BDAu;
  x0 += k0; x1 += k1;
#define TFR(r) { x0 += x1; x1 = rotl32d(x1, r); x1 ^= x0; }
  TFR(13) TFR(15) TFR(26) TFR(6)   x0 += k1;  x1 += ks2 + 1u;
  TFR(17) TFR(29) TFR(16) TFR(24)  x0 += ks2; x1 += k0 + 2u;
  TFR(13) TFR(15) TFR(26) TFR(6)   x0 += k0;  x1 += k1 + 3u;
  TFR(17) TFR(29) TFR(16) TFR(24)  x0 += k1;  x1 += ks2 + 4u;
  TFR(13) TFR(15) TFR(26) TFR(6)   x0 += ks2; x1 += k0 + 5u;
#undef TFR
  y0 = x0; y1 = x1;
}

// Partitionable-mode 32-bit random bits for flat index idx (hi word of 64-bit iota == 0)
__device__ __forceinline__ unsigned tf_bits(unsigned k0, unsigned k1, unsigned idx){
  unsigned y0, y1; tf2x32_dev(k0, k1, 0u, idx, y0, y1); return y0 ^ y1;
}

__device__ __forceinline__ float u01_from_bits(unsigned bits){
  return __uint_as_float((bits >> 9) | 0x3f800000u) - 1.0f;
}

// XLA f32 ErfInv polynomial
__device__ __forceinline__ float erfinv_xla(float x){
  float w = -log1pf(-x*x);
  float p;
  if (w < 5.0f){
    w = w - 2.5f;
    p = 2.81022636e-08f;
    p = fmaf(p,w, 3.43273939e-07f);
    p = fmaf(p,w,-3.5233877e-06f);
    p = fmaf(p,w,-4.39150654e-06f);
    p = fmaf(p,w, 0.00021858087f);
    p = fmaf(p,w,-0.00125372503f);
    p = fmaf(p,w,-0.00417768164f);
    p = fmaf(p,w, 0.246640727f);
    p = fmaf(p,w, 1.50140941f);
  } else {
    w = sqrtf(w) - 3.0f;
    p = -0.000200214257f;
    p = fmaf(p,w, 0.000100950558f);
    p = fmaf(p,w, 0.00134934322f);
    p = fmaf(p,w,-0.00367342844f);
    p = fmaf(p,w, 0.00573950773f);
    p = fmaf(p,w,-0.0076224613f);
    p = fmaf(p,w, 0.00943887047f);
    p = fmaf(p,w, 1.00167406f);
    p = fmaf(p,w, 2.83297682f);
  }
  return p*x;
}

// ---------------- setup kernels ----------------
// Detect int64 vs int32 edge buffer: int64 => odd u32 words (high words) all zero.
__global__ void k_detect(const unsigned* __restrict__ raw, int* flag){
  unsigned v = raw[2*threadIdx.x + 1];
  unsigned long long m = __ballot(v == 0u);
  if (threadIdx.x == 0) *flag = (m == 0xFFFFFFFFFFFFFFFFull) ? 1 : 0;
}

__global__ void k_convert(const unsigned* __restrict__ raw, const int* __restrict__ flag,
                          int E, int* __restrict__ src, int* __restrict__ dst){
  int e = blockIdx.x*256 + threadIdx.x; if (e >= E) return;
  if (*flag){ src[e] = (int)raw[2*(size_t)e]; dst[e] = (int)raw[2*((size_t)E + e)]; }
  else      { const int* r = (const int*)raw; src[e] = r[e]; dst[e] = r[E + e]; }
}

__global__ void k_count(const int* __restrict__ dst, int E, int* __restrict__ cnt){
  int e = blockIdx.x*256 + threadIdx.x;
  if (e < E) atomicAdd(&cnt[dst[e]], 1);
}

// single-block exclusive scan + dis = rsqrt(deg) (deg = cnt+1 for self loop)
__global__ void k_scan(const int* __restrict__ cnt, int N, int* __restrict__ rowptr,
                       float* __restrict__ dis){
  __shared__ int sums[1024];
  int tid = threadIdx.x;
  int chunk = (N + 1023) / 1024;
  int lo = tid*chunk, hi = lo + chunk; if (hi > N) hi = N; if (lo > N) lo = N;
  int s = 0;
  for (int i = lo; i < hi; i++) s += cnt[i];
  sums[tid] = s; __syncthreads();
  for (int off = 1; off < 1024; off <<= 1){
    int v = (tid >= off) ? sums[tid - off] : 0;
    __syncthreads();
    sums[tid] += v;
    __syncthreads();
  }
  int prefix = (tid == 0) ? 0 : sums[tid-1];
  for (int i = lo; i < hi; i++){
    rowptr[i] = prefix;
    int c = cnt[i];
    prefix += c;
    dis[i] = 1.0f / sqrtf((float)(c + 1));
  }
  if (tid == 1023) rowptr[N] = sums[1023];
}

__global__ void k_fill(const int* __restrict__ src, const int* __restrict__ dst, int E,
                       const int* __restrict__ rowptr, int* __restrict__ cnt,
                       const float* __restrict__ dis,
                       int* __restrict__ csr_src, float* __restrict__ csr_w){
  int e = blockIdx.x*256 + threadIdx.x; if (e >= E) return;
  int d = dst[e], s = src[e];
  int pos = atomicAdd(&cnt[d], 1);
  int slot = rowptr[d] + pos;
  csr_src[slot] = s;
  csr_w[slot] = dis[s]*dis[d];
}

// ---- degree-sort permutation (descending): equal-degree rows co-scheduled per wave ----
__global__ void k_histo(const int* __restrict__ cnt, int N, int* __restrict__ bcnt){
  int n = blockIdx.x*256 + threadIdx.x;
  if (n < N) atomicAdd(&bcnt[min(cnt[n], 63)], 1);
}

__global__ void k_bscan(int* __restrict__ bcnt){   // 1 block, 64 threads
  __shared__ int sh[64];
  int b = threadIdx.x;
  sh[b] = bcnt[b]; __syncthreads();
  int off = 0;
  for (int b2 = b+1; b2 < 64; b2++) off += sh[b2];  // descending: high degree first
  bcnt[b] = off;
}

__global__ void k_permfill(const int* __restrict__ cnt, int N, int* __restrict__ bcnt,
                           int* __restrict__ perm){
  int n = blockIdx.x*256 + threadIdx.x; if (n >= N) return;
  int pos = atomicAdd(&bcnt[min(cnt[n], 63)], 1);
  perm[pos] = n;
}

// ---------------- h0 = x@proj_w + b, plus layer-0 quantization (delta=1) ----------------
__global__ __launch_bounds__(256) void k_h0(
  const float* __restrict__ x, const float* __restrict__ W, const float* __restrict__ bias,
  float* __restrict__ h0, float* __restrict__ hq, unsigned kq0, unsigned kq1, int N)
{
  __shared__ float xs[64*65];     // 64 nodes x 64 K-chunk, pad 65
  __shared__ float wsh[64*96];    // K-chunk x 96
  int tid = threadIdx.x; int n0 = blockIdx.x*64;
  int cg = tid & 15, ng = tid >> 4; int c0 = cg*6;
  float acc[4][6];
#pragma unroll
  for (int i=0;i<4;i++) for (int j=0;j<6;j++) acc[i][j]=0.f;
  for (int kc=0; kc<2; kc++){
    if (kc) __syncthreads();
    for (int q=tid; q<1536; q+=256)
      ((float4*)wsh)[q] = ((const float4*)(W + kc*64*96))[q];
    for (int q=tid; q<1024; q+=256){
      int g=q*4; int r=g>>6, col=g&63;
      int n=n0+r; int ns = n<N ? n : N-1;
      float4 v = ((const float4*)(x + (size_t)ns*128 + kc*64))[col>>2];
      xs[r*65+col]=v.x; xs[r*65+col+1]=v.y; xs[r*65+col+2]=v.z; xs[r*65+col+3]=v.w;
    }
    __syncthreads();
    for (int k=0;k<64;k++){
      float wv[6];
#pragma unroll
      for (int j=0;j<6;j++) wv[j]=wsh[k*96 + c0 + j];
#pragma unroll
      for (int i=0;i<4;i++){
        float xv = xs[(ng*4+i)*65 + k];
#pragma unroll
        for (int j=0;j<6;j++) acc[i][j] = fmaf(xv, wv[j], acc[i][j]);
      }
    }
  }
#pragma unroll
  for (int i=0;i<4;i++){
    int n = n0 + ng*4 + i; if (n >= N) continue;
#pragma unroll
    for (int j=0;j<6;j++){
      int c = c0 + j; int p = n*96 + c;
      float v = acc[i][j] + bias[c];
      h0[p] = v;
      unsigned bq = tf_bits(kq0, kq1, (unsigned)p);
      float b = u01_from_bits(bq) - 0.5f;     // delta = 1
      hq[p] = floorf(v + b) - b;
    }
  }
}

// ---------------- CSR aggregation: t = 0.9*(sum hq[src]*norm + self) + 0.1*h0 ----------------
// v2: dim3(32,8) -> 2 rows per wave exactly; lanes 0..23 do float4 gathers (16 B);
// unroll-by-4 edge pipeline (4 gathers in flight); degree-sorted perm kills divergence.
__global__ __launch_bounds__(256) void k_agg(
  const float* __restrict__ hq, const float* __restrict__ h0, const float* __restrict__ dis,
  const int* __restrict__ rowptr, const int* __restrict__ csr_src, const float* __restrict__ csr_w,
  const int* __restrict__ perm, float* __restrict__ tout, int N)
{
  int tx = threadIdx.x;                     // 0..31
  int row = blockIdx.x*8 + threadIdx.y;
  if (row >= N) return;
  int n = perm[row];
  if (tx >= 24) return;                     // 24 float4 lanes cover 96 channels
  const float4* hq4 = (const float4*)hq;
  float d = dis[n];
  int lo = rowptr[n], hi = rowptr[n+1];
  float4 self = hq4[(size_t)n*24 + tx];
  float dd = d*d;
  float ax = self.x*dd, ay = self.y*dd, az = self.z*dd, aw = self.w*dd;
  for (int s = lo; s < hi; s += 4){
    int   sn[4];
    float w[4];
#pragma unroll
    for (int j = 0; j < 4; j++){
      bool hv = (s + j) < hi;
      sn[j] = hv ? csr_src[s + j] : csr_src[s];
      w[j]  = hv ? csr_w[s + j]   : 0.0f;
    }
    float4 g0 = hq4[(size_t)sn[0]*24 + tx];
    float4 g1 = hq4[(size_t)sn[1]*24 + tx];
    float4 g2 = hq4[(size_t)sn[2]*24 + tx];
    float4 g3 = hq4[(size_t)sn[3]*24 + tx];
    ax = fmaf(g0.x, w[0], ax); ay = fmaf(g0.y, w[0], ay);
    az = fmaf(g0.z, w[0], az); aw = fmaf(g0.w, w[0], aw);
    ax = fmaf(g1.x, w[1], ax); ay = fmaf(g1.y, w[1], ay);
    az = fmaf(g1.z, w[1], az); aw = fmaf(g1.w, w[1], aw);
    ax = fmaf(g2.x, w[2], ax); ay = fmaf(g2.y, w[2], ay);
    az = fmaf(g2.z, w[2], az); aw = fmaf(g2.w, w[2], aw);
    ax = fmaf(g3.x, w[3], ax); ay = fmaf(g3.y, w[3], ay);
    az = fmaf(g3.z, w[3], az); aw = fmaf(g3.w, w[3], aw);
  }
  const float4* h04 = (const float4*)h0;
  float4 hz = h04[(size_t)n*24 + tx];
  float4 o;
  o.x = 0.9f*ax + 0.1f*hz.x;
  o.y = 0.9f*ay + 0.1f*hz.y;
  o.z = 0.9f*az + 0.1f*hz.z;
  o.w = 0.9f*aw + 0.1f*hz.w;
  ((float4*)tout)[(size_t)n*24 + tx] = o;
}

// ---------------- M = t@W; h = (1-b)t + b*M; +noise; relu; dropout; next-layer quant ----------------
// 8 col-groups (12 cols, 3x ds_read_b128, conflict-free bank-quads) x 32 node-groups x 2 nodes.
// W staged in two 48-row K-chunks -> LDS 44032 B -> 3 blocks/CU.
__global__ __launch_bounds__(256, 3) void k_mmpost(
  const float* __restrict__ tbuf, const float* __restrict__ W,
  float betaf, float ombf,
  unsigned ke0, unsigned ke1, unsigned kd0, unsigned kd1,
  unsigned kq0, unsigned kq1, float delta_n, float invdelta_n,
  int do_dropout, int write_h,
  float* __restrict__ hq_out, float* __restrict__ h_out, int N)
{
  __shared__ float ts[64*100];   // 25600 B, stride 100 (b128-aligned, 2-way-free banks)
  __shared__ float wsh[48*96];   // 18432 B, K-chunk, row-major
  int tid = threadIdx.x; int n0 = blockIdx.x*64;

  // stage t tile: 64 rows x 96 cols = 1536 float4
  for (int q = tid; q < 1536; q += 256){
    int r = q / 24, c4 = (q % 24) * 4;
    int n = n0 + r; int ns = n < N ? n : N - 1;
    float4 v = ((const float4*)(tbuf + (size_t)ns*96))[c4 >> 2];
    *((float4*)&ts[r*100 + c4]) = v;
  }

  int cg = tid & 7, ng = tid >> 3;   // cg 0..7, ng 0..31
  int c0 = cg * 12;
  int r0 = ng * 2;
  float acc[2][12];
#pragma unroll
  for (int i = 0; i < 2; i++)
#pragma unroll
    for (int j = 0; j < 12; j++) acc[i][j] = 0.f;

  for (int chunk = 0; chunk < 2; chunk++){
    __syncthreads();   // first: ts staged; later: previous chunk consumed
    for (int q = tid; q < 1152; q += 256)
      ((float4*)wsh)[q] = ((const float4*)(W + chunk*48*96))[q];
    __syncthreads();
#pragma unroll 4
    for (int kk = 0; kk < 48; kk++){
      int k = chunk*48 + kk;
      float4 w0 = *((const float4*)&wsh[kk*96 + c0]);
      float4 w1 = *((const float4*)&wsh[kk*96 + c0 + 4]);
      float4 w2 = *((const float4*)&wsh[kk*96 + c0 + 8]);
      float xv0 = ts[r0*100 + k];
      float xv1 = ts[(r0+1)*100 + k];
      acc[0][0] = fmaf(xv0, w0.x, acc[0][0]);  acc[0][1] = fmaf(xv0, w0.y, acc[0][1]);
      acc[0][2] = fmaf(xv0, w0.z, acc[0][2]);  acc[0][3] = fmaf(xv0, w0.w, acc[0][3]);
      acc[0][4] = fmaf(xv0, w1.x, acc[0][4]);  acc[0][5] = fmaf(xv0, w1.y, acc[0][5]);
      acc[0][6] = fmaf(xv0, w1.z, acc[0][6]);  acc[0][7] = fmaf(xv0, w1.w, acc[0][7]);
      acc[0][8] = fmaf(xv0, w2.x, acc[0][8]);  acc[0][9] = fmaf(xv0, w2.y, acc[0][9]);
      acc[0][10]= fmaf(xv0, w2.z, acc[0][10]); acc[0][11]= fmaf(xv0, w2.w, acc[0][11]);
      acc[1][0] = fmaf(xv1, w0.x, acc[1][0]);  acc[1][1] = fmaf(xv1, w0.y, acc[1][1]);
      acc[1][2] = fmaf(xv1, w0.z, acc[1][2]);  acc[1][3] = fmaf(xv1, w0.w, acc[1][3]);
      acc[1][4] = fmaf(xv1, w1.x, acc[1][4]);  acc[1][5] = fmaf(xv1, w1.y, acc[1][5]);
      acc[1][6] = fmaf(xv1, w1.z, acc[1][6]);  acc[1][7] = fmaf(xv1, w1.w, acc[1][7]);
      acc[1][8] = fmaf(xv1, w2.x, acc[1][8]);  acc[1][9] = fmaf(xv1, w2.y, acc[1][9]);
      acc[1][10]= fmaf(xv1, w2.z, acc[1][10]); acc[1][11]= fmaf(xv1, w2.w, acc[1][11]);
    }
  }

  const float LO = __uint_as_float(0xBF7FFFFFu);   // nextafter(-1,0)
#pragma unroll
  for (int i = 0; i < 2; i++){
    int n = n0 + r0 + i; if (n >= N) continue;
    float res[12];
#pragma unroll
    for (int j = 0; j < 12; j++){
      int c = c0 + j; int p = n*96 + c;
      float tv = ts[(r0+i)*100 + c];
      float hv = ombf*tv + betaf*acc[i][j];
      unsigned be = tf_bits(ke0, ke1, (unsigned)p);
      float uv = fmaxf(LO, u01_from_bits(be)*2.0f + LO);
      hv += 0.01f * (1.41421356f * erfinv_xla(uv));
      hv = fmaxf(hv, 0.0f);
      if (do_dropout){
        unsigned bd = tf_bits(kd0, kd1, (unsigned)p);
        hv = (bd < 0x80000000u) ? hv*2.0f : 0.0f;   // uniform<0.5 keep, /0.5
      }
      if (!write_h){
        unsigned bq = tf_bits(kq0, kq1, (unsigned)p);
        float b = (u01_from_bits(bq) - 0.5f)*delta_n;
        hv = floorf((hv + b)*invdelta_n)*delta_n - b;
      }
      res[j] = hv;
    }
    float* dst = (write_h ? h_out : hq_out) + (size_t)n*96 + c0;
#pragma unroll
    for (int j4 = 0; j4 < 3; j4++)
      *((float4*)&dst[j4*4]) = make_float4(res[j4*4], res[j4*4+1], res[j4*4+2], res[j4*4+3]);
  }
}

// ---------------- out = [h0, h] @ out_w + out_b ----------------
__global__ __launch_bounds__(256) void k_final(
  const float* __restrict__ h0, const float* __restrict__ h,
  const float* __restrict__ W, const float* __restrict__ bias,
  float* __restrict__ out, int N)
{
  __shared__ float xs[64*97];
  __shared__ float wsh[96*40];
  int tid = threadIdx.x; int n0 = blockIdx.x*64;
  int cg = tid & 7, ng = tid >> 3; int c0 = cg*5;
  float acc[2][5];
#pragma unroll
  for (int i=0;i<2;i++) for (int j=0;j<5;j++) acc[i][j]=0.f;
  for (int ph=0; ph<2; ph++){
    if (ph) __syncthreads();
    const float* xsrc = ph ? h : h0;
    for (int q=tid; q<960; q+=256)
      ((float4*)wsh)[q] = ((const float4*)(W + ph*96*40))[q];
    for (int q=tid; q<1536; q+=256){
      int g=q*4; int r=g/96, col=g%96;
      int n=n0+r; int ns = n<N ? n : N-1;
      float4 v = ((const float4*)(xsrc + (size_t)ns*96))[col>>2];
      xs[r*97+col]=v.x; xs[r*97+col+1]=v.y; xs[r*97+col+2]=v.z; xs[r*97+col+3]=v.w;
    }
    __syncthreads();
    for (int k=0;k<96;k++){
      float wv[5];
#pragma unroll
      for (int j=0;j<5;j++) wv[j]=wsh[k*40 + c0 + j];
#pragma unroll
      for (int i=0;i<2;i++){
        float xv = xs[(ng*2+i)*97 + k];
#pragma unroll
        for (int j=0;j<5;j++) acc[i][j] = fmaf(xv, wv[j], acc[i][j]);
      }
    }
  }
#pragma unroll
  for (int i=0;i<2;i++){
    int n = n0 + ng*2 + i; if (n >= N) continue;
#pragma unroll
    for (int j=0;j<5;j++)
      out[(size_t)n*40 + c0 + j] = acc[i][j] + bias[c0 + j];
  }
}

// ---------------- host ----------------
static void tf_host(uint32_t k0, uint32_t k1, uint32_t x0, uint32_t x1,
                    uint32_t &y0, uint32_t &y1){
  uint32_t ks2 = k0 ^ k1 ^ 0x1BD11BDAu;
  x0 += k0; x1 += k1;
  auto R = [&](int r){ x0 += x1; x1 = (x1<<r)|(x1>>(32-r)); x1 ^= x0; };
  R(13);R(15);R(26);R(6);   x0 += k1;  x1 += ks2 + 1u;
  R(17);R(29);R(16);R(24);  x0 += ks2; x1 += k0 + 2u;
  R(13);R(15);R(26);R(6);   x0 += k0;  x1 += k1 + 3u;
  R(17);R(29);R(16);R(24);  x0 += k1;  x1 += ks2 + 4u;
  R(13);R(15);R(26);R(6);   x0 += ks2; x1 += k0 + 5u;
  y0 = x0; y1 = x1;
}

extern "C" void kernel_launch(void* const* d_in, const int* in_sizes, int n_in,
                              void* d_out, int out_size, void* d_ws, size_t ws_size,
                              hipStream_t stream)
{
  const float*    x       = (const float*)d_in[0];
  const unsigned* eraw    = (const unsigned*)d_in[1];
  const float*    proj_w  = (const float*)d_in[2];
  const float*    proj_b  = (const float*)d_in[3];
  const float*    conv_w  = (const float*)d_in[4];
  const float*    out_w   = (const float*)d_in[5];
  const float*    out_b   = (const float*)d_in[6];
  float* out = (float*)d_out;

  const int N = in_sizes[0] / INC;     // 50000
  const int E = in_sizes[1] / 2;       // 800000
  const size_t NH = (size_t)N * HID;

  float* ws     = (float*)d_ws;
  float* h0     = ws;
  float* hq     = h0 + NH;
  float* tb     = hq + NH;
  float* hb     = tb + NH;
  float* dis    = hb + NH;
  int*   cnt    = (int*)(dis + N);
  int*   rowptr = cnt + N;
  int*   csr_src= rowptr + (N + 1);
  float* csr_w  = (float*)(csr_src + E);
  int*   srcb   = (int*)(csr_w + E);
  int*   dstb   = srcb + E;
  int*   flag   = dstb + E;
  int*   perm   = flag + 1;
  int*   bcnt   = perm + N;
  (void)ws_size; (void)n_in; (void)out_size;

  // JAX key chain: key(42) -> per layer split(key,4) (partitionable foldlike)
  uint32_t kq[8][2], ke[8][2], kd[8][2];
  {
    uint32_t K0 = 0u, K1 = 42u;
    for (int k = 0; k < 8; k++){
      uint32_t y0, y1;
      tf_host(K0, K1, 0u, 0u, y0, y1); kq[k][0]=y0; kq[k][1]=y1;
      tf_host(K0, K1, 0u, 1u, y0, y1); ke[k][0]=y0; ke[k][1]=y1;
      tf_host(K0, K1, 0u, 2u, y0, y1); kd[k][0]=y0; kd[k][1]=y1;
      tf_host(K0, K1, 0u, 3u, y0, y1); K0=y0; K1=y1;
    }
  }

  const int gE  = (E + 255)/256;
  const int gN  = (N + 255)/256;
  const int gMM = (N + 63)/64;

  hipMemsetAsync(cnt, 0, (size_t)N*4, stream);
  hipMemsetAsync(bcnt, 0, 64*4, stream);
  k_detect <<<1, 64, 0, stream>>>(eraw, flag);
  k_convert<<<gE, 256, 0, stream>>>(eraw, flag, E, srcb, dstb);
  k_count  <<<gE, 256, 0, stream>>>(dstb, E, cnt);
  k_scan   <<<1, 1024, 0, stream>>>(cnt, N, rowptr, dis);
  k_histo  <<<gN, 256, 0, stream>>>(cnt, N, bcnt);
  k_bscan  <<<1, 64, 0, stream>>>(bcnt);
  k_permfill<<<gN, 256, 0, stream>>>(cnt, N, bcnt, perm);
  hipMemsetAsync(cnt, 0, (size_t)N*4, stream);
  k_fill   <<<gE, 256, 0, stream>>>(srcb, dstb, E, rowptr, cnt, dis, csr_src, csr_w);

  k_h0<<<gMM, 256, 0, stream>>>(x, proj_w, proj_b, h0, hq, kq[0][0], kq[0][1], N);

  for (int k = 0; k < 8; k++){
    k_agg<<<(N+7)/8, dim3(32,8), 0, stream>>>(hq, h0, dis, rowptr, csr_src, csr_w, perm, tb, N);
    double bd = log(0.5/(double)(k+1) + 1.0);
    float betaf = (float)bd;
    float ombf  = (float)(1.0 - bd);
    int last = (k == 7);
    float dn  = 1.0f/(float)(1 << (k+1));
    float idn = (float)(1 << (k+1));
    k_mmpost<<<gMM, 256, 0, stream>>>(tb, conv_w + (size_t)k*HID*HID, betaf, ombf,
      ke[k][0], ke[k][1], kd[k][0], kd[k][1],
      last?0u:kq[k+1][0], last?0u:kq[k+1][1], dn, idn,
      !last, last, hq, hb, N);
  }

  k_final<<<gMM, 256, 0, stream>>>(h0, hb, out_w, out_b, out, N);
}

// Round 4
// 1312.929 us; speedup vs baseline: 1.4878x; 1.2179x over previous
//
#include <hip/hip_runtime.h>
#include <cstdint>
#include <cmath>

#define HID 96
#define INC 128
#define OUTC 40

// ---------------- threefry2x32 (JAX exact) ----------------
__device__ __forceinline__ unsigned rotl32d(unsigned x, int r){ return (x<<r)|(x>>(32-r)); }

__device__ __forceinline__ void tf2x32_dev(unsigned k0, unsigned k1, unsigned x0, unsigned x1,
                                           unsigned &y0, unsigned &y1){
  unsigned ks2 = k0 ^ k1 ^ 0x1BD11BDAu;
  x0 += k0; x1 += k1;
#define TFR(r) { x0 += x1; x1 = rotl32d(x1, r); x1 ^= x0; }
  TFR(13) TFR(15) TFR(26) TFR(6)   x0 += k1;  x1 += ks2 + 1u;
  TFR(17) TFR(29) TFR(16) TFR(24)  x0 += ks2; x1 += k0 + 2u;
  TFR(13) TFR(15) TFR(26) TFR(6)   x0 += k0;  x1 += k1 + 3u;
  TFR(17) TFR(29) TFR(16) TFR(24)  x0 += k1;  x1 += ks2 + 4u;
  TFR(13) TFR(15) TFR(26) TFR(6)   x0 += ks2; x1 += k0 + 5u;
#undef TFR
  y0 = x0; y1 = x1;
}

// Partitionable-mode 32-bit random bits for flat index idx (hi word of 64-bit iota == 0)
__device__ __forceinline__ unsigned tf_bits(unsigned k0, unsigned k1, unsigned idx){
  unsigned y0, y1; tf2x32_dev(k0, k1, 0u, idx, y0, y1); return y0 ^ y1;
}

__device__ __forceinline__ float u01_from_bits(unsigned bits){
  return __uint_as_float((bits >> 9) | 0x3f800000u) - 1.0f;
}

// XLA f32 ErfInv polynomial
__device__ __forceinline__ float erfinv_xla(float x){
  float w = -log1pf(-x*x);
  float p;
  if (w < 5.0f){
    w = w - 2.5f;
    p = 2.81022636e-08f;
    p = fmaf(p,w, 3.43273939e-07f);
    p = fmaf(p,w,-3.5233877e-06f);
    p = fmaf(p,w,-4.39150654e-06f);
    p = fmaf(p,w, 0.00021858087f);
    p = fmaf(p,w,-0.00125372503f);
    p = fmaf(p,w,-0.00417768164f);
    p = fmaf(p,w, 0.246640727f);
    p = fmaf(p,w, 1.50140941f);
  } else {
    w = sqrtf(w) - 3.0f;
    p = -0.000200214257f;
    p = fmaf(p,w, 0.000100950558f);
    p = fmaf(p,w, 0.00134934322f);
    p = fmaf(p,w,-0.00367342844f);
    p = fmaf(p,w, 0.00573950773f);
    p = fmaf(p,w,-0.0076224613f);
    p = fmaf(p,w, 0.00943887047f);
    p = fmaf(p,w, 1.00167406f);
    p = fmaf(p,w, 2.83297682f);
  }
  return p*x;
}

// ---------------- setup kernels ----------------
// Detect int64 vs int32 edge buffer: int64 => odd u32 words (high words) all zero.
__global__ void k_detect(const unsigned* __restrict__ raw, int* flag){
  unsigned v = raw[2*threadIdx.x + 1];
  unsigned long long m = __ballot(v == 0u);
  if (threadIdx.x == 0) *flag = (m == 0xFFFFFFFFFFFFFFFFull) ? 1 : 0;
}

__global__ void k_convert(const unsigned* __restrict__ raw, const int* __restrict__ flag,
                          int E, int* __restrict__ src, int* __restrict__ dst){
  int e = blockIdx.x*256 + threadIdx.x; if (e >= E) return;
  if (*flag){ src[e] = (int)raw[2*(size_t)e]; dst[e] = (int)raw[2*((size_t)E + e)]; }
  else      { const int* r = (const int*)raw; src[e] = r[e]; dst[e] = r[E + e]; }
}

__global__ void k_count(const int* __restrict__ dst, int E, int* __restrict__ cnt){
  int e = blockIdx.x*256 + threadIdx.x;
  if (e < E) atomicAdd(&cnt[dst[e]], 1);
}

// single-block exclusive scan + dis = rsqrt(deg) (deg = cnt+1 for self loop)
__global__ void k_scan(const int* __restrict__ cnt, int N, int* __restrict__ rowptr,
                       float* __restrict__ dis){
  __shared__ int sums[1024];
  int tid = threadIdx.x;
  int chunk = (N + 1023) / 1024;
  int lo = tid*chunk, hi = lo + chunk; if (hi > N) hi = N; if (lo > N) lo = N;
  int s = 0;
  for (int i = lo; i < hi; i++) s += cnt[i];
  sums[tid] = s; __syncthreads();
  for (int off = 1; off < 1024; off <<= 1){
    int v = (tid >= off) ? sums[tid - off] : 0;
    __syncthreads();
    sums[tid] += v;
    __syncthreads();
  }
  int prefix = (tid == 0) ? 0 : sums[tid-1];
  for (int i = lo; i < hi; i++){
    rowptr[i] = prefix;
    int c = cnt[i];
    prefix += c;
    dis[i] = 1.0f / sqrtf((float)(c + 1));
  }
  if (tid == 1023) rowptr[N] = sums[1023];
}

__global__ void k_fill(const int* __restrict__ src, const int* __restrict__ dst, int E,
                       const int* __restrict__ rowptr, int* __restrict__ cnt,
                       const float* __restrict__ dis,
                       int* __restrict__ csr_src, float* __restrict__ csr_w){
  int e = blockIdx.x*256 + threadIdx.x; if (e >= E) return;
  int d = dst[e], s = src[e];
  int pos = atomicAdd(&cnt[d], 1);
  int slot = rowptr[d] + pos;
  csr_src[slot] = s;
  csr_w[slot] = dis[s]*dis[d];
}

// ---- degree-sort permutation (descending): equal-degree rows co-scheduled per wave ----
// Round 3: per-block LDS pre-aggregation (G12) — the round-2 version did 50K global
// atomics onto 64 addresses = 143 µs of pure serialization per kernel.
__global__ void k_histo(const int* __restrict__ cnt, int N, int* __restrict__ bcnt){
  __shared__ int lh[64];
  int tid = threadIdx.x;
  if (tid < 64) lh[tid] = 0;
  __syncthreads();
  int n = blockIdx.x*256 + tid;
  if (n < N) atomicAdd(&lh[min(cnt[n], 63)], 1);
  __syncthreads();
  if (tid < 64){
    int c = lh[tid];
    if (c > 0) atomicAdd(&bcnt[tid], c);
  }
}

__global__ void k_bscan(int* __restrict__ bcnt){   // 1 block, 64 threads
  __shared__ int sh[64];
  int b = threadIdx.x;
  sh[b] = bcnt[b]; __syncthreads();
  int off = 0;
  for (int b2 = b+1; b2 < 64; b2++) off += sh[b2];  // descending: high degree first
  bcnt[b] = off;
}

__global__ void k_permfill(const int* __restrict__ cnt, int N, int* __restrict__ bcnt,
                           int* __restrict__ perm){
  __shared__ int lh[64];     // pass 1: local counts / ranks; pass 2: global bases
  int tid = threadIdx.x;
  if (tid < 64) lh[tid] = 0;
  __syncthreads();
  int n = blockIdx.x*256 + tid;
  int b = 0, r = 0;
  if (n < N){
    b = min(cnt[n], 63);
    r = atomicAdd(&lh[b], 1);          // local rank within (block, bucket)
  }
  __syncthreads();
  if (tid < 64){
    int c = lh[tid];
    lh[tid] = (c > 0) ? atomicAdd(&bcnt[tid], c) : 0;   // reserve global range
  }
  __syncthreads();
  if (n < N) perm[lh[b] + r] = n;
}

// ---------------- h0 = x@proj_w + b, plus layer-0 quantization (delta=1) ----------------
__global__ __launch_bounds__(256) void k_h0(
  const float* __restrict__ x, const float* __restrict__ W, const float* __restrict__ bias,
  float* __restrict__ h0, float* __restrict__ hq, unsigned kq0, unsigned kq1, int N)
{
  __shared__ float xs[64*65];     // 64 nodes x 64 K-chunk, pad 65
  __shared__ float wsh[64*96];    // K-chunk x 96
  int tid = threadIdx.x; int n0 = blockIdx.x*64;
  int cg = tid & 15, ng = tid >> 4; int c0 = cg*6;
  float acc[4][6];
#pragma unroll
  for (int i=0;i<4;i++) for (int j=0;j<6;j++) acc[i][j]=0.f;
  for (int kc=0; kc<2; kc++){
    if (kc) __syncthreads();
    for (int q=tid; q<1536; q+=256)
      ((float4*)wsh)[q] = ((const float4*)(W + kc*64*96))[q];
    for (int q=tid; q<1024; q+=256){
      int g=q*4; int r=g>>6, col=g&63;
      int n=n0+r; int ns = n<N ? n : N-1;
      float4 v = ((const float4*)(x + (size_t)ns*128 + kc*64))[col>>2];
      xs[r*65+col]=v.x; xs[r*65+col+1]=v.y; xs[r*65+col+2]=v.z; xs[r*65+col+3]=v.w;
    }
    __syncthreads();
    for (int k=0;k<64;k++){
      float wv[6];
#pragma unroll
      for (int j=0;j<6;j++) wv[j]=wsh[k*96 + c0 + j];
#pragma unroll
      for (int i=0;i<4;i++){
        float xv = xs[(ng*4+i)*65 + k];
#pragma unroll
        for (int j=0;j<6;j++) acc[i][j] = fmaf(xv, wv[j], acc[i][j]);
      }
    }
  }
#pragma unroll
  for (int i=0;i<4;i++){
    int n = n0 + ng*4 + i; if (n >= N) continue;
#pragma unroll
    for (int j=0;j<6;j++){
      int c = c0 + j; int p = n*96 + c;
      float v = acc[i][j] + bias[c];
      h0[p] = v;
      unsigned bq = tf_bits(kq0, kq1, (unsigned)p);
      float b = u01_from_bits(bq) - 0.5f;     // delta = 1
      hq[p] = floorf(v + b) - b;
    }
  }
}

// ---------------- CSR aggregation: t = 0.9*(sum hq[src]*norm + self) + 0.1*h0 ----------------
// dim3(32,8) -> 2 rows per wave; lanes 0..23 do float4 gathers (16 B);
// unroll-by-4 edge pipeline (4 gathers in flight); degree-sorted perm kills divergence.
__global__ __launch_bounds__(256) void k_agg(
  const float* __restrict__ hq, const float* __restrict__ h0, const float* __restrict__ dis,
  const int* __restrict__ rowptr, const int* __restrict__ csr_src, const float* __restrict__ csr_w,
  const int* __restrict__ perm, float* __restrict__ tout, int N)
{
  int tx = threadIdx.x;                     // 0..31
  int row = blockIdx.x*8 + threadIdx.y;
  if (row >= N) return;
  int n = perm[row];
  if (tx >= 24) return;                     // 24 float4 lanes cover 96 channels
  const float4* hq4 = (const float4*)hq;
  float d = dis[n];
  int lo = rowptr[n], hi = rowptr[n+1];
  float4 self = hq4[(size_t)n*24 + tx];
  float dd = d*d;
  float ax = self.x*dd, ay = self.y*dd, az = self.z*dd, aw = self.w*dd;
  for (int s = lo; s < hi; s += 4){
    int   sn[4];
    float w[4];
#pragma unroll
    for (int j = 0; j < 4; j++){
      bool hv = (s + j) < hi;
      sn[j] = hv ? csr_src[s + j] : csr_src[s];
      w[j]  = hv ? csr_w[s + j]   : 0.0f;
    }
    float4 g0 = hq4[(size_t)sn[0]*24 + tx];
    float4 g1 = hq4[(size_t)sn[1]*24 + tx];
    float4 g2 = hq4[(size_t)sn[2]*24 + tx];
    float4 g3 = hq4[(size_t)sn[3]*24 + tx];
    ax = fmaf(g0.x, w[0], ax); ay = fmaf(g0.y, w[0], ay);
    az = fmaf(g0.z, w[0], az); aw = fmaf(g0.w, w[0], aw);
    ax = fmaf(g1.x, w[1], ax); ay = fmaf(g1.y, w[1], ay);
    az = fmaf(g1.z, w[1], az); aw = fmaf(g1.w, w[1], aw);
    ax = fmaf(g2.x, w[2], ax); ay = fmaf(g2.y, w[2], ay);
    az = fmaf(g2.z, w[2], az); aw = fmaf(g2.w, w[2], aw);
    ax = fmaf(g3.x, w[3], ax); ay = fmaf(g3.y, w[3], ay);
    az = fmaf(g3.z, w[3], az); aw = fmaf(g3.w, w[3], aw);
  }
  const float4* h04 = (const float4*)h0;
  float4 hz = h04[(size_t)n*24 + tx];
  float4 o;
  o.x = 0.9f*ax + 0.1f*hz.x;
  o.y = 0.9f*ay + 0.1f*hz.y;
  o.z = 0.9f*az + 0.1f*hz.z;
  o.w = 0.9f*aw + 0.1f*hz.w;
  ((float4*)tout)[(size_t)n*24 + tx] = o;
}

// ---------------- M = t@W; h = (1-b)t + b*M; +noise; relu; dropout; next-layer quant ----------------
// 8 col-groups (12 cols, 3x ds_read_b128, conflict-free bank-quads) x 32 node-groups x 2 nodes.
// W staged in two 48-row K-chunks -> LDS 44032 B -> 3 blocks/CU.
__global__ __launch_bounds__(256, 3) void k_mmpost(
  const float* __restrict__ tbuf, const float* __restrict__ W,
  float betaf, float ombf,
  unsigned ke0, unsigned ke1, unsigned kd0, unsigned kd1,
  unsigned kq0, unsigned kq1, float delta_n, float invdelta_n,
  int do_dropout, int write_h,
  float* __restrict__ hq_out, float* __restrict__ h_out, int N)
{
  __shared__ float ts[64*100];   // 25600 B, stride 100 (b128-aligned, 2-way-free banks)
  __shared__ float wsh[48*96];   // 18432 B, K-chunk, row-major
  int tid = threadIdx.x; int n0 = blockIdx.x*64;

  // stage t tile: 64 rows x 96 cols = 1536 float4
  for (int q = tid; q < 1536; q += 256){
    int r = q / 24, c4 = (q % 24) * 4;
    int n = n0 + r; int ns = n < N ? n : N - 1;
    float4 v = ((const float4*)(tbuf + (size_t)ns*96))[c4 >> 2];
    *((float4*)&ts[r*100 + c4]) = v;
  }

  int cg = tid & 7, ng = tid >> 3;   // cg 0..7, ng 0..31
  int c0 = cg * 12;
  int r0 = ng * 2;
  float acc[2][12];
#pragma unroll
  for (int i = 0; i < 2; i++)
#pragma unroll
    for (int j = 0; j < 12; j++) acc[i][j] = 0.f;

  for (int chunk = 0; chunk < 2; chunk++){
    __syncthreads();   // first: ts staged; later: previous chunk consumed
    for (int q = tid; q < 1152; q += 256)
      ((float4*)wsh)[q] = ((const float4*)(W + chunk*48*96))[q];
    __syncthreads();
#pragma unroll 4
    for (int kk = 0; kk < 48; kk++){
      int k = chunk*48 + kk;
      float4 w0 = *((const float4*)&wsh[kk*96 + c0]);
      float4 w1 = *((const float4*)&wsh[kk*96 + c0 + 4]);
      float4 w2 = *((const float4*)&wsh[kk*96 + c0 + 8]);
      float xv0 = ts[r0*100 + k];
      float xv1 = ts[(r0+1)*100 + k];
      acc[0][0] = fmaf(xv0, w0.x, acc[0][0]);  acc[0][1] = fmaf(xv0, w0.y, acc[0][1]);
      acc[0][2] = fmaf(xv0, w0.z, acc[0][2]);  acc[0][3] = fmaf(xv0, w0.w, acc[0][3]);
      acc[0][4] = fmaf(xv0, w1.x, acc[0][4]);  acc[0][5] = fmaf(xv0, w1.y, acc[0][5]);
      acc[0][6] = fmaf(xv0, w1.z, acc[0][6]);  acc[0][7] = fmaf(xv0, w1.w, acc[0][7]);
      acc[0][8] = fmaf(xv0, w2.x, acc[0][8]);  acc[0][9] = fmaf(xv0, w2.y, acc[0][9]);
      acc[0][10]= fmaf(xv0, w2.z, acc[0][10]); acc[0][11]= fmaf(xv0, w2.w, acc[0][11]);
      acc[1][0] = fmaf(xv1, w0.x, acc[1][0]);  acc[1][1] = fmaf(xv1, w0.y, acc[1][1]);
      acc[1][2] = fmaf(xv1, w0.z, acc[1][2]);  acc[1][3] = fmaf(xv1, w0.w, acc[1][3]);
      acc[1][4] = fmaf(xv1, w1.x, acc[1][4]);  acc[1][5] = fmaf(xv1, w1.y, acc[1][5]);
      acc[1][6] = fmaf(xv1, w1.z, acc[1][6]);  acc[1][7] = fmaf(xv1, w1.w, acc[1][7]);
      acc[1][8] = fmaf(xv1, w2.x, acc[1][8]);  acc[1][9] = fmaf(xv1, w2.y, acc[1][9]);
      acc[1][10]= fmaf(xv1, w2.z, acc[1][10]); acc[1][11]= fmaf(xv1, w2.w, acc[1][11]);
    }
  }

  const float LO = __uint_as_float(0xBF7FFFFFu);   // nextafter(-1,0)
#pragma unroll
  for (int i = 0; i < 2; i++){
    int n = n0 + r0 + i; if (n >= N) continue;
    float res[12];
#pragma unroll
    for (int j = 0; j < 12; j++){
      int c = c0 + j; int p = n*96 + c;
      float tv = ts[(r0+i)*100 + c];
      float hv = ombf*tv + betaf*acc[i][j];
      unsigned be = tf_bits(ke0, ke1, (unsigned)p);
      float uv = fmaxf(LO, u01_from_bits(be)*2.0f + LO);
      hv += 0.01f * (1.41421356f * erfinv_xla(uv));
      hv = fmaxf(hv, 0.0f);
      if (do_dropout){
        unsigned bd = tf_bits(kd0, kd1, (unsigned)p);
        hv = (bd < 0x80000000u) ? hv*2.0f : 0.0f;   // uniform<0.5 keep, /0.5
      }
      if (!write_h){
        unsigned bq = tf_bits(kq0, kq1, (unsigned)p);
        float b = (u01_from_bits(bq) - 0.5f)*delta_n;
        hv = floorf((hv + b)*invdelta_n)*delta_n - b;
      }
      res[j] = hv;
    }
    float* dst = (write_h ? h_out : hq_out) + (size_t)n*96 + c0;
#pragma unroll
    for (int j4 = 0; j4 < 3; j4++)
      *((float4*)&dst[j4*4]) = make_float4(res[j4*4], res[j4*4+1], res[j4*4+2], res[j4*4+3]);
  }
}

// ---------------- out = [h0, h] @ out_w + out_b ----------------
__global__ __launch_bounds__(256) void k_final(
  const float* __restrict__ h0, const float* __restrict__ h,
  const float* __restrict__ W, const float* __restrict__ bias,
  float* __restrict__ out, int N)
{
  __shared__ float xs[64*97];
  __shared__ float wsh[96*40];
  int tid = threadIdx.x; int n0 = blockIdx.x*64;
  int cg = tid & 7, ng = tid >> 3; int c0 = cg*5;
  float acc[2][5];
#pragma unroll
  for (int i=0;i<2;i++) for (int j=0;j<5;j++) acc[i][j]=0.f;
  for (int ph=0; ph<2; ph++){
    if (ph) __syncthreads();
    const float* xsrc = ph ? h : h0;
    for (int q=tid; q<960; q+=256)
      ((float4*)wsh)[q] = ((const float4*)(W + ph*96*40))[q];
    for (int q=tid; q<1536; q+=256){
      int g=q*4; int r=g/96, col=g%96;
      int n=n0+r; int ns = n<N ? n : N-1;
      float4 v = ((const float4*)(xsrc + (size_t)ns*96))[col>>2];
      xs[r*97+col]=v.x; xs[r*97+col+1]=v.y; xs[r*97+col+2]=v.z; xs[r*97+col+3]=v.w;
    }
    __syncthreads();
    for (int k=0;k<96;k++){
      float wv[5];
#pragma unroll
      for (int j=0;j<5;j++) wv[j]=wsh[k*40 + c0 + j];
#pragma unroll
      for (int i=0;i<2;i++){
        float xv = xs[(ng*2+i)*97 + k];
#pragma unroll
        for (int j=0;j<5;j++) acc[i][j] = fmaf(xv, wv[j], acc[i][j]);
      }
    }
  }
#pragma unroll
  for (int i=0;i<2;i++){
    int n = n0 + ng*2 + i; if (n >= N) continue;
#pragma unroll
    for (int j=0;j<5;j++)
      out[(size_t)n*40 + c0 + j] = acc[i][j] + bias[c0 + j];
  }
}

// ---------------- host ----------------
static void tf_host(uint32_t k0, uint32_t k1, uint32_t x0, uint32_t x1,
                    uint32_t &y0, uint32_t &y1){
  uint32_t ks2 = k0 ^ k1 ^ 0x1BD11BDAu;
  x0 += k0; x1 += k1;
  auto R = [&](int r){ x0 += x1; x1 = (x1<<r)|(x1>>(32-r)); x1 ^= x0; };
  R(13);R(15);R(26);R(6);   x0 += k1;  x1 += ks2 + 1u;
  R(17);R(29);R(16);R(24);  x0 += ks2; x1 += k0 + 2u;
  R(13);R(15);R(26);R(6);   x0 += k0;  x1 += k1 + 3u;
  R(17);R(29);R(16);R(24);  x0 += k1;  x1 += ks2 + 4u;
  R(13);R(15);R(26);R(6);   x0 += ks2; x1 += k0 + 5u;
  y0 = x0; y1 = x1;
}

extern "C" void kernel_launch(void* const* d_in, const int* in_sizes, int n_in,
                              void* d_out, int out_size, void* d_ws, size_t ws_size,
                              hipStream_t stream)
{
  const float*    x       = (const float*)d_in[0];
  const unsigned* eraw    = (const unsigned*)d_in[1];
  const float*    proj_w  = (const float*)d_in[2];
  const float*    proj_b  = (const float*)d_in[3];
  const float*    conv_w  = (const float*)d_in[4];
  const float*    out_w   = (const float*)d_in[5];
  const float*    out_b   = (const float*)d_in[6];
  float* out = (float*)d_out;

  const int N = in_sizes[0] / INC;     // 50000
  const int E = in_sizes[1] / 2;       // 800000
  const size_t NH = (size_t)N * HID;

  float* ws     = (float*)d_ws;
  float* h0     = ws;
  float* hq     = h0 + NH;
  float* tb     = hq + NH;
  float* hb     = tb + NH;
  float* dis    = hb + NH;
  int*   cnt    = (int*)(dis + N);
  int*   rowptr = cnt + N;
  int*   csr_src= rowptr + (N + 1);
  float* csr_w  = (float*)(csr_src + E);
  int*   srcb   = (int*)(csr_w + E);
  int*   dstb   = srcb + E;
  int*   flag   = dstb + E;
  int*   perm   = flag + 1;
  int*   bcnt   = perm + N;
  (void)ws_size; (void)n_in; (void)out_size;

  // JAX key chain: key(42) -> per layer split(key,4) (partitionable foldlike)
  uint32_t kq[8][2], ke[8][2], kd[8][2];
  {
    uint32_t K0 = 0u, K1 = 42u;
    for (int k = 0; k < 8; k++){
      uint32_t y0, y1;
      tf_host(K0, K1, 0u, 0u, y0, y1); kq[k][0]=y0; kq[k][1]=y1;
      tf_host(K0, K1, 0u, 1u, y0, y1); ke[k][0]=y0; ke[k][1]=y1;
      tf_host(K0, K1, 0u, 2u, y0, y1); kd[k][0]=y0; kd[k][1]=y1;
      tf_host(K0, K1, 0u, 3u, y0, y1); K0=y0; K1=y1;
    }
  }

  const int gE  = (E + 255)/256;
  const int gN  = (N + 255)/256;
  const int gMM = (N + 63)/64;

  hipMemsetAsync(cnt, 0, (size_t)N*4, stream);
  hipMemsetAsync(bcnt, 0, 64*4, stream);
  k_detect <<<1, 64, 0, stream>>>(eraw, flag);
  k_convert<<<gE, 256, 0, stream>>>(eraw, flag, E, srcb, dstb);
  k_count  <<<gE, 256, 0, stream>>>(dstb, E, cnt);
  k_scan   <<<1, 1024, 0, stream>>>(cnt, N, rowptr, dis);
  k_histo  <<<gN, 256, 0, stream>>>(cnt, N, bcnt);
  k_bscan  <<<1, 64, 0, stream>>>(bcnt);
  k_permfill<<<gN, 256, 0, stream>>>(cnt, N, bcnt, perm);
  hipMemsetAsync(cnt, 0, (size_t)N*4, stream);
  k_fill   <<<gE, 256, 0, stream>>>(srcb, dstb, E, rowptr, cnt, dis, csr_src, csr_w);

  k_h0<<<gMM, 256, 0, stream>>>(x, proj_w, proj_b, h0, hq, kq[0][0], kq[0][1], N);

  for (int k = 0; k < 8; k++){
    k_agg<<<(N+7)/8, dim3(32,8), 0, stream>>>(hq, h0, dis, rowptr, csr_src, csr_w, perm, tb, N);
    double bd = log(0.5/(double)(k+1) + 1.0);
    float betaf = (float)bd;
    float ombf  = (float)(1.0 - bd);
    int last = (k == 7);
    float dn  = 1.0f/(float)(1 << (k+1));
    float idn = (float)(1 << (k+1));
    k_mmpost<<<gMM, 256, 0, stream>>>(tb, conv_w + (size_t)k*HID*HID, betaf, ombf,
      ke[k][0], ke[k][1], kd[k][0], kd[k][1],
      last?0u:kq[k+1][0], last?0u:kq[k+1][1], dn, idn,
      !last, last, hq, hb, N);
  }

  k_final<<<gMM, 256, 0, stream>>>(h0, hb, out_w, out_b, out, N);
}

// Round 5
// 1229.583 us; speedup vs baseline: 1.5886x; 1.0678x over previous
//
#include <hip/hip_runtime.h>
#include <cstdint>
#include <cmath>

#define HID 96
#define INC 128
#define OUTC 40

// ---------------- threefry2x32 (JAX exact) ----------------
__device__ __forceinline__ unsigned rotl32d(unsigned x, int r){ return (x<<r)|(x>>(32-r)); }

__device__ __forceinline__ void tf2x32_dev(unsigned k0, unsigned k1, unsigned x0, unsigned x1,
                                           unsigned &y0, unsigned &y1){
  unsigned ks2 = k0 ^ k1 ^ 0x1BD11BDAu;
  x0 += k0; x1 += k1;
#define TFR(r) { x0 += x1; x1 = rotl32d(x1, r); x1 ^= x0; }
  TFR(13) TFR(15) TFR(26) TFR(6)   x0 += k1;  x1 += ks2 + 1u;
  TFR(17) TFR(29) TFR(16) TFR(24)  x0 += ks2; x1 += k0 + 2u;
  TFR(13) TFR(15) TFR(26) TFR(6)   x0 += k0;  x1 += k1 + 3u;
  TFR(17) TFR(29) TFR(16) TFR(24)  x0 += k1;  x1 += ks2 + 4u;
  TFR(13) TFR(15) TFR(26) TFR(6)   x0 += ks2; x1 += k0 + 5u;
#undef TFR
  y0 = x0; y1 = x1;
}

// Partitionable-mode 32-bit random bits for flat index idx (hi word of 64-bit iota == 0)
__device__ __forceinline__ unsigned tf_bits(unsigned k0, unsigned k1, unsigned idx){
  unsigned y0, y1; tf2x32_dev(k0, k1, 0u, idx, y0, y1); return y0 ^ y1;
}

__device__ __forceinline__ float u01_from_bits(unsigned bits){
  return __uint_as_float((bits >> 9) | 0x3f800000u) - 1.0f;
}

// XLA f32 ErfInv polynomial
__device__ __forceinline__ float erfinv_xla(float x){
  float w = -log1pf(-x*x);
  float p;
  if (w < 5.0f){
    w = w - 2.5f;
    p = 2.81022636e-08f;
    p = fmaf(p,w, 3.43273939e-07f);
    p = fmaf(p,w,-3.5233877e-06f);
    p = fmaf(p,w,-4.39150654e-06f);
    p = fmaf(p,w, 0.00021858087f);
    p = fmaf(p,w,-0.00125372503f);
    p = fmaf(p,w,-0.00417768164f);
    p = fmaf(p,w, 0.246640727f);
    p = fmaf(p,w, 1.50140941f);
  } else {
    w = sqrtf(w) - 3.0f;
    p = -0.000200214257f;
    p = fmaf(p,w, 0.000100950558f);
    p = fmaf(p,w, 0.00134934322f);
    p = fmaf(p,w,-0.00367342844f);
    p = fmaf(p,w, 0.00573950773f);
    p = fmaf(p,w,-0.0076224613f);
    p = fmaf(p,w, 0.00943887047f);
    p = fmaf(p,w, 1.00167406f);
    p = fmaf(p,w, 2.83297682f);
  }
  return p*x;
}

// ---------------- setup kernels ----------------
// Detect int64 vs int32 edge buffer: int64 => odd u32 words (high words) all zero.
__global__ void k_detect(const unsigned* __restrict__ raw, int* flag){
  unsigned v = raw[2*threadIdx.x + 1];
  unsigned long long m = __ballot(v == 0u);
  if (threadIdx.x == 0) *flag = (m == 0xFFFFFFFFFFFFFFFFull) ? 1 : 0;
}

__global__ void k_convert(const unsigned* __restrict__ raw, const int* __restrict__ flag,
                          int E, int* __restrict__ src, int* __restrict__ dst){
  int e = blockIdx.x*256 + threadIdx.x; if (e >= E) return;
  if (*flag){ src[e] = (int)raw[2*(size_t)e]; dst[e] = (int)raw[2*((size_t)E + e)]; }
  else      { const int* r = (const int*)raw; src[e] = r[e]; dst[e] = r[E + e]; }
}

__global__ void k_count(const int* __restrict__ dst, int E, int* __restrict__ cnt){
  int e = blockIdx.x*256 + threadIdx.x;
  if (e < E) atomicAdd(&cnt[dst[e]], 1);
}

// ---- parallel 3-kernel scan (round 4: replaces the 106 µs single-block k_scan) ----
__global__ void k_psum(const int* __restrict__ cnt, int N, int* __restrict__ psum){
  __shared__ int sh[256];
  int tid = threadIdx.x; int n = blockIdx.x*256 + tid;
  sh[tid] = (n < N) ? cnt[n] : 0;
  __syncthreads();
  for (int off = 128; off > 0; off >>= 1){
    if (tid < off) sh[tid] += sh[tid + off];
    __syncthreads();
  }
  if (tid == 0) psum[blockIdx.x] = sh[0];
}

__global__ void k_pscan(int* __restrict__ psum, int nb){   // 1 block, 256 threads
  __shared__ int sh[256];
  int tid = threadIdx.x;
  int v = (tid < nb) ? psum[tid] : 0;
  sh[tid] = v; __syncthreads();
  for (int off = 1; off < 256; off <<= 1){
    int t = (tid >= off) ? sh[tid - off] : 0;
    __syncthreads();
    sh[tid] += t;
    __syncthreads();
  }
  if (tid < nb) psum[tid] = sh[tid] - v;   // exclusive
}

__global__ void k_rowptr(const int* __restrict__ cnt, const int* __restrict__ psum,
                         int N, int E, int* __restrict__ rowptr, float* __restrict__ dis){
  __shared__ int sh[256];
  int tid = threadIdx.x; int n = blockIdx.x*256 + tid;
  int v = (n < N) ? cnt[n] : 0;
  sh[tid] = v; __syncthreads();
  for (int off = 1; off < 256; off <<= 1){
    int t = (tid >= off) ? sh[tid - off] : 0;
    __syncthreads();
    sh[tid] += t;
    __syncthreads();
  }
  if (n < N){
    rowptr[n] = psum[blockIdx.x] + sh[tid] - v;
    dis[n] = 1.0f / sqrtf((float)(v + 1));
  }
  if (n == N-1) rowptr[N] = E;
}

__global__ void k_fill(const int* __restrict__ src, const int* __restrict__ dst, int E,
                       const int* __restrict__ rowptr, int* __restrict__ cnt,
                       const float* __restrict__ dis,
                       int* __restrict__ csr_src, float* __restrict__ csr_w){
  int e = blockIdx.x*256 + threadIdx.x; if (e >= E) return;
  int d = dst[e], s = src[e];
  int pos = atomicAdd(&cnt[d], 1);
  int slot = rowptr[d] + pos;
  csr_src[slot] = s;
  csr_w[slot] = dis[s]*dis[d];
}

// ---- degree-sort permutation (descending): degree-uniform 64-row tiles for k_layer ----
__global__ void k_histo(const int* __restrict__ cnt, int N, int* __restrict__ bcnt){
  __shared__ int lh[64];
  int tid = threadIdx.x;
  if (tid < 64) lh[tid] = 0;
  __syncthreads();
  int n = blockIdx.x*256 + tid;
  if (n < N) atomicAdd(&lh[min(cnt[n], 63)], 1);
  __syncthreads();
  if (tid < 64){
    int c = lh[tid];
    if (c > 0) atomicAdd(&bcnt[tid], c);
  }
}

__global__ void k_bscan(int* __restrict__ bcnt){   // 1 block, 64 threads
  __shared__ int sh[64];
  int b = threadIdx.x;
  sh[b] = bcnt[b]; __syncthreads();
  int off = 0;
  for (int b2 = b+1; b2 < 64; b2++) off += sh[b2];  // descending: high degree first
  bcnt[b] = off;
}

__global__ void k_permfill(const int* __restrict__ cnt, int N, int* __restrict__ bcnt,
                           int* __restrict__ perm){
  __shared__ int lh[64];     // pass 1: local counts / ranks; pass 2: global bases
  int tid = threadIdx.x;
  if (tid < 64) lh[tid] = 0;
  __syncthreads();
  int n = blockIdx.x*256 + tid;
  int b = 0, r = 0;
  if (n < N){
    b = min(cnt[n], 63);
    r = atomicAdd(&lh[b], 1);          // local rank within (block, bucket)
  }
  __syncthreads();
  if (tid < 64){
    int c = lh[tid];
    lh[tid] = (c > 0) ? atomicAdd(&bcnt[tid], c) : 0;   // reserve global range
  }
  __syncthreads();
  if (n < N) perm[lh[b] + r] = n;
}

// ---------------- h0 = x@proj_w + b, plus layer-0 quantization (delta=1) ----------------
__global__ __launch_bounds__(256) void k_h0(
  const float* __restrict__ x, const float* __restrict__ W, const float* __restrict__ bias,
  float* __restrict__ h0, float* __restrict__ hq, unsigned kq0, unsigned kq1, int N)
{
  __shared__ float xs[64*65];     // 64 nodes x 64 K-chunk, pad 65
  __shared__ float wsh[64*96];    // K-chunk x 96
  int tid = threadIdx.x; int n0 = blockIdx.x*64;
  int cg = tid & 15, ng = tid >> 4; int c0 = cg*6;
  float acc[4][6];
#pragma unroll
  for (int i=0;i<4;i++) for (int j=0;j<6;j++) acc[i][j]=0.f;
  for (int kc=0; kc<2; kc++){
    if (kc) __syncthreads();
    for (int q=tid; q<1536; q+=256)
      ((float4*)wsh)[q] = ((const float4*)(W + kc*64*96))[q];
    for (int q=tid; q<1024; q+=256){
      int g=q*4; int r=g>>6, col=g&63;
      int n=n0+r; int ns = n<N ? n : N-1;
      float4 v = ((const float4*)(x + (size_t)ns*128 + kc*64))[col>>2];
      xs[r*65+col]=v.x; xs[r*65+col+1]=v.y; xs[r*65+col+2]=v.z; xs[r*65+col+3]=v.w;
    }
    __syncthreads();
    for (int k=0;k<64;k++){
      float wv[6];
#pragma unroll
      for (int j=0;j<6;j++) wv[j]=wsh[k*96 + c0 + j];
#pragma unroll
      for (int i=0;i<4;i++){
        float xv = xs[(ng*4+i)*65 + k];
#pragma unroll
        for (int j=0;j<6;j++) acc[i][j] = fmaf(xv, wv[j], acc[i][j]);
      }
    }
  }
#pragma unroll
  for (int i=0;i<4;i++){
    int n = n0 + ng*4 + i; if (n >= N) continue;
#pragma unroll
    for (int j=0;j<6;j++){
      int c = c0 + j; int p = n*96 + c;
      float v = acc[i][j] + bias[c];
      h0[p] = v;
      unsigned bq = tf_bits(kq0, kq1, (unsigned)p);
      float b = u01_from_bits(bq) - 0.5f;     // delta = 1
      hq[p] = floorf(v + b) - b;
    }
  }
}

// ---------------- fused per-layer kernel ----------------
// Phase 1: gather t = 0.9*(Σ hq[src]*w + self*d²) + 0.1*h0 for a 64-row tile (perm order,
//          degree-uniform) straight into LDS. Phase 2: t@W (two 48-row W chunks) + epilogue
//          (residual mix, threefry noise, relu, dropout, next-layer quantization), writing
//          hq_out (or h_out for the last layer) row-scattered. hq ping-pongs across layers.
__global__ __launch_bounds__(256, 3) void k_layer(
  const float* __restrict__ hq_in, const float* __restrict__ h0, const float* __restrict__ dis,
  const int* __restrict__ rowptr, const int* __restrict__ csr_src, const float* __restrict__ csr_w,
  const int* __restrict__ perm, const float* __restrict__ W,
  float betaf, float ombf,
  unsigned ke0, unsigned ke1, unsigned kd0, unsigned kd1,
  unsigned kq0, unsigned kq1, float delta_n, float invdelta_n,
  int do_dropout, int write_h,
  float* __restrict__ hq_out, float* __restrict__ h_out, int N)
{
  __shared__ float ts[64*100];   // 25600 B t tile, stride 100
  __shared__ float wsh[48*96];   // 18432 B W K-chunk
  __shared__ int rowmap[64];     // node id per tile row
  int tid = threadIdx.x;
  int tx = tid & 31, ty = tid >> 5;    // 8 rows in flight
  int n0 = blockIdx.x*64;

  const float4* hq4 = (const float4*)hq_in;
  const float4* h04 = (const float4*)h0;

  // ---- phase 1: gather 64 rows, 8 passes of 8 concurrent rows ----
#pragma unroll 1
  for (int pass = 0; pass < 8; pass++){
    int r = pass*8 + ty;
    int row = n0 + r;
    int n = (row < N) ? perm[row] : -1;
    if (tx == 0) rowmap[r] = n;
    if (tx < 24){
      float4 o = make_float4(0.f, 0.f, 0.f, 0.f);
      if (n >= 0){
        float d = dis[n];
        int lo = rowptr[n], hi = rowptr[n+1];
        float4 self = hq4[(size_t)n*24 + tx];
        float dd = d*d;
        float ax = self.x*dd, ay = self.y*dd, az = self.z*dd, aw = self.w*dd;
        for (int s = lo; s < hi; s += 8){
          int   sn[8];
          float w[8];
#pragma unroll
          for (int j = 0; j < 8; j++){
            bool hv = (s + j) < hi;
            sn[j] = hv ? csr_src[s + j] : csr_src[s];
            w[j]  = hv ? csr_w[s + j]   : 0.0f;
          }
          float4 g[8];
#pragma unroll
          for (int j = 0; j < 8; j++) g[j] = hq4[(size_t)sn[j]*24 + tx];
#pragma unroll
          for (int j = 0; j < 8; j++){
            ax = fmaf(g[j].x, w[j], ax); ay = fmaf(g[j].y, w[j], ay);
            az = fmaf(g[j].z, w[j], az); aw = fmaf(g[j].w, w[j], aw);
          }
        }
        float4 hz = h04[(size_t)n*24 + tx];
        o.x = 0.9f*ax + 0.1f*hz.x;
        o.y = 0.9f*ay + 0.1f*hz.y;
        o.z = 0.9f*az + 0.1f*hz.z;
        o.w = 0.9f*aw + 0.1f*hz.w;
      }
      *((float4*)&ts[r*100 + tx*4]) = o;
    }
  }

  // ---- phase 2: matmul + epilogue ----
  int cg = tid & 7, ng = tid >> 3;   // cg 0..7, ng 0..31
  int c0 = cg * 12;
  int r0 = ng * 2;
  float acc[2][12];
#pragma unroll
  for (int i = 0; i < 2; i++)
#pragma unroll
    for (int j = 0; j < 12; j++) acc[i][j] = 0.f;

  for (int chunk = 0; chunk < 2; chunk++){
    __syncthreads();   // first: ts+rowmap staged; later: previous chunk consumed
    for (int q = tid; q < 1152; q += 256)
      ((float4*)wsh)[q] = ((const float4*)(W + chunk*48*96))[q];
    __syncthreads();
#pragma unroll 4
    for (int kk = 0; kk < 48; kk++){
      int k = chunk*48 + kk;
      float4 w0 = *((const float4*)&wsh[kk*96 + c0]);
      float4 w1 = *((const float4*)&wsh[kk*96 + c0 + 4]);
      float4 w2 = *((const float4*)&wsh[kk*96 + c0 + 8]);
      float xv0 = ts[r0*100 + k];
      float xv1 = ts[(r0+1)*100 + k];
      acc[0][0] = fmaf(xv0, w0.x, acc[0][0]);  acc[0][1] = fmaf(xv0, w0.y, acc[0][1]);
      acc[0][2] = fmaf(xv0, w0.z, acc[0][2]);  acc[0][3] = fmaf(xv0, w0.w, acc[0][3]);
      acc[0][4] = fmaf(xv0, w1.x, acc[0][4]);  acc[0][5] = fmaf(xv0, w1.y, acc[0][5]);
      acc[0][6] = fmaf(xv0, w1.z, acc[0][6]);  acc[0][7] = fmaf(xv0, w1.w, acc[0][7]);
      acc[0][8] = fmaf(xv0, w2.x, acc[0][8]);  acc[0][9] = fmaf(xv0, w2.y, acc[0][9]);
      acc[0][10]= fmaf(xv0, w2.z, acc[0][10]); acc[0][11]= fmaf(xv0, w2.w, acc[0][11]);
      acc[1][0] = fmaf(xv1, w0.x, acc[1][0]);  acc[1][1] = fmaf(xv1, w0.y, acc[1][1]);
      acc[1][2] = fmaf(xv1, w0.z, acc[1][2]);  acc[1][3] = fmaf(xv1, w0.w, acc[1][3]);
      acc[1][4] = fmaf(xv1, w1.x, acc[1][4]);  acc[1][5] = fmaf(xv1, w1.y, acc[1][5]);
      acc[1][6] = fmaf(xv1, w1.z, acc[1][6]);  acc[1][7] = fmaf(xv1, w1.w, acc[1][7]);
      acc[1][8] = fmaf(xv1, w2.x, acc[1][8]);  acc[1][9] = fmaf(xv1, w2.y, acc[1][9]);
      acc[1][10]= fmaf(xv1, w2.z, acc[1][10]); acc[1][11]= fmaf(xv1, w2.w, acc[1][11]);
    }
  }

  const float LO = __uint_as_float(0xBF7FFFFFu);   // nextafter(-1,0)
#pragma unroll
  for (int i = 0; i < 2; i++){
    int n = rowmap[r0 + i]; if (n < 0) continue;
    float res[12];
#pragma unroll
    for (int j = 0; j < 12; j++){
      int c = c0 + j; int p = n*96 + c;
      float tv = ts[(r0+i)*100 + c];
      float hv = ombf*tv + betaf*acc[i][j];
      unsigned be = tf_bits(ke0, ke1, (unsigned)p);
      float uv = fmaxf(LO, u01_from_bits(be)*2.0f + LO);
      hv += 0.01f * (1.41421356f * erfinv_xla(uv));
      hv = fmaxf(hv, 0.0f);
      if (do_dropout){
        unsigned bd = tf_bits(kd0, kd1, (unsigned)p);
        hv = (bd < 0x80000000u) ? hv*2.0f : 0.0f;   // uniform<0.5 keep, /0.5
      }
      if (!write_h){
        unsigned bq = tf_bits(kq0, kq1, (unsigned)p);
        float b = (u01_from_bits(bq) - 0.5f)*delta_n;
        hv = floorf((hv + b)*invdelta_n)*delta_n - b;
      }
      res[j] = hv;
    }
    float* dst = (write_h ? h_out : hq_out) + (size_t)n*96 + c0;
#pragma unroll
    for (int j4 = 0; j4 < 3; j4++)
      *((float4*)&dst[j4*4]) = make_float4(res[j4*4], res[j4*4+1], res[j4*4+2], res[j4*4+3]);
  }
}

// ---------------- out = [h0, h] @ out_w + out_b ----------------
__global__ __launch_bounds__(256) void k_final(
  const float* __restrict__ h0, const float* __restrict__ h,
  const float* __restrict__ W, const float* __restrict__ bias,
  float* __restrict__ out, int N)
{
  __shared__ float xs[64*97];
  __shared__ float wsh[96*40];
  int tid = threadIdx.x; int n0 = blockIdx.x*64;
  int cg = tid & 7, ng = tid >> 3; int c0 = cg*5;
  float acc[2][5];
#pragma unroll
  for (int i=0;i<2;i++) for (int j=0;j<5;j++) acc[i][j]=0.f;
  for (int ph=0; ph<2; ph++){
    if (ph) __syncthreads();
    const float* xsrc = ph ? h : h0;
    for (int q=tid; q<960; q+=256)
      ((float4*)wsh)[q] = ((const float4*)(W + ph*96*40))[q];
    for (int q=tid; q<1536; q+=256){
      int g=q*4; int r=g/96, col=g%96;
      int n=n0+r; int ns = n<N ? n : N-1;
      float4 v = ((const float4*)(xsrc + (size_t)ns*96))[col>>2];
      xs[r*97+col]=v.x; xs[r*97+col+1]=v.y; xs[r*97+col+2]=v.z; xs[r*97+col+3]=v.w;
    }
    __syncthreads();
    for (int k=0;k<96;k++){
      float wv[5];
#pragma unroll
      for (int j=0;j<5;j++) wv[j]=wsh[k*40 + c0 + j];
#pragma unroll
      for (int i=0;i<2;i++){
        float xv = xs[(ng*2+i)*97 + k];
#pragma unroll
        for (int j=0;j<5;j++) acc[i][j] = fmaf(xv, wv[j], acc[i][j]);
      }
    }
  }
#pragma unroll
  for (int i=0;i<2;i++){
    int n = n0 + ng*2 + i; if (n >= N) continue;
#pragma unroll
    for (int j=0;j<5;j++)
      out[(size_t)n*40 + c0 + j] = acc[i][j] + bias[c0 + j];
  }
}

// ---------------- host ----------------
static void tf_host(uint32_t k0, uint32_t k1, uint32_t x0, uint32_t x1,
                    uint32_t &y0, uint32_t &y1){
  uint32_t ks2 = k0 ^ k1 ^ 0x1BD11BDAu;
  x0 += k0; x1 += k1;
  auto R = [&](int r){ x0 += x1; x1 = (x1<<r)|(x1>>(32-r)); x1 ^= x0; };
  R(13);R(15);R(26);R(6);   x0 += k1;  x1 += ks2 + 1u;
  R(17);R(29);R(16);R(24);  x0 += ks2; x1 += k0 + 2u;
  R(13);R(15);R(26);R(6);   x0 += k0;  x1 += k1 + 3u;
  R(17);R(29);R(16);R(24);  x0 += k1;  x1 += ks2 + 4u;
  R(13);R(15);R(26);R(6);   x0 += ks2; x1 += k0 + 5u;
  y0 = x0; y1 = x1;
}

extern "C" void kernel_launch(void* const* d_in, const int* in_sizes, int n_in,
                              void* d_out, int out_size, void* d_ws, size_t ws_size,
                              hipStream_t stream)
{
  const float*    x       = (const float*)d_in[0];
  const unsigned* eraw    = (const unsigned*)d_in[1];
  const float*    proj_w  = (const float*)d_in[2];
  const float*    proj_b  = (const float*)d_in[3];
  const float*    conv_w  = (const float*)d_in[4];
  const float*    out_w   = (const float*)d_in[5];
  const float*    out_b   = (const float*)d_in[6];
  float* out = (float*)d_out;

  const int N = in_sizes[0] / INC;     // 50000
  const int E = in_sizes[1] / 2;       // 800000
  const size_t NH = (size_t)N * HID;

  float* ws     = (float*)d_ws;
  float* h0     = ws;
  float* hq     = h0 + NH;       // ping
  float* tb     = hq + NH;       // pong
  float* hb     = tb + NH;
  float* dis    = hb + NH;
  int*   cnt    = (int*)(dis + N);
  int*   rowptr = cnt + N;
  int*   csr_src= rowptr + (N + 1);
  float* csr_w  = (float*)(csr_src + E);
  int*   srcb   = (int*)(csr_w + E);
  int*   dstb   = srcb + E;
  int*   flag   = dstb + E;
  int*   perm   = flag + 1;
  int*   bcnt   = perm + N;
  int*   psum   = bcnt + 64;
  (void)ws_size; (void)n_in; (void)out_size;

  // JAX key chain: key(42) -> per layer split(key,4) (partitionable foldlike)
  uint32_t kq[8][2], ke[8][2], kd[8][2];
  {
    uint32_t K0 = 0u, K1 = 42u;
    for (int k = 0; k < 8; k++){
      uint32_t y0, y1;
      tf_host(K0, K1, 0u, 0u, y0, y1); kq[k][0]=y0; kq[k][1]=y1;
      tf_host(K0, K1, 0u, 1u, y0, y1); ke[k][0]=y0; ke[k][1]=y1;
      tf_host(K0, K1, 0u, 2u, y0, y1); kd[k][0]=y0; kd[k][1]=y1;
      tf_host(K0, K1, 0u, 3u, y0, y1); K0=y0; K1=y1;
    }
  }

  const int gE  = (E + 255)/256;
  const int gN  = (N + 255)/256;   // also the partial-sum block count (196 <= 256)
  const int gMM = (N + 63)/64;

  hipMemsetAsync(cnt, 0, (size_t)N*4, stream);
  hipMemsetAsync(bcnt, 0, 64*4, stream);
  k_detect <<<1, 64, 0, stream>>>(eraw, flag);
  k_convert<<<gE, 256, 0, stream>>>(eraw, flag, E, srcb, dstb);
  k_count  <<<gE, 256, 0, stream>>>(dstb, E, cnt);
  k_psum   <<<gN, 256, 0, stream>>>(cnt, N, psum);
  k_pscan  <<<1, 256, 0, stream>>>(psum, gN);
  k_rowptr <<<gN, 256, 0, stream>>>(cnt, psum, N, E, rowptr, dis);
  k_histo  <<<gN, 256, 0, stream>>>(cnt, N, bcnt);
  k_bscan  <<<1, 64, 0, stream>>>(bcnt);
  k_permfill<<<gN, 256, 0, stream>>>(cnt, N, bcnt, perm);
  hipMemsetAsync(cnt, 0, (size_t)N*4, stream);
  k_fill   <<<gE, 256, 0, stream>>>(srcb, dstb, E, rowptr, cnt, dis, csr_src, csr_w);

  k_h0<<<gMM, 256, 0, stream>>>(x, proj_w, proj_b, h0, hq, kq[0][0], kq[0][1], N);

  for (int k = 0; k < 8; k++){
    double bd = log(0.5/(double)(k+1) + 1.0);
    float betaf = (float)bd;
    float ombf  = (float)(1.0 - bd);
    int last = (k == 7);
    float dn  = 1.0f/(float)(1 << (k+1));
    float idn = (float)(1 << (k+1));
    const float* hin  = (k & 1) ? tb : hq;   // ping-pong: no same-buffer read/write race
    float*       hout = (k & 1) ? hq : tb;
    k_layer<<<gMM, 256, 0, stream>>>(hin, h0, dis, rowptr, csr_src, csr_w, perm,
      conv_w + (size_t)k*HID*HID, betaf, ombf,
      ke[k][0], ke[k][1], kd[k][0], kd[k][1],
      last?0u:kq[k+1][0], last?0u:kq[k+1][1], dn, idn,
      !last, last, hout, hb, N);
  }

  k_final<<<gMM, 256, 0, stream>>>(h0, hb, out_w, out_b, out, N);
}

// Round 6
// 1076.514 us; speedup vs baseline: 1.8145x; 1.1422x over previous
//
#include <hip/hip_runtime.h>
#include <cstdint>
#include <cmath>

#define HID 96
#define INC 128
#define OUTC 40

// ---------------- threefry2x32 (JAX exact) ----------------
__device__ __forceinline__ unsigned rotl32d(unsigned x, int r){ return (x<<r)|(x>>(32-r)); }

__device__ __forceinline__ void tf2x32_dev(unsigned k0, unsigned k1, unsigned x0, unsigned x1,
                                           unsigned &y0, unsigned &y1){
  unsigned ks2 = k0 ^ k1 ^ 0x1BD11BDAu;
  x0 += k0; x1 += k1;
#define TFR(r) { x0 += x1; x1 = rotl32d(x1, r); x1 ^= x0; }
  TFR(13) TFR(15) TFR(26) TFR(6)   x0 += k1;  x1 += ks2 + 1u;
  TFR(17) TFR(29) TFR(16) TFR(24)  x0 += ks2; x1 += k0 + 2u;
  TFR(13) TFR(15) TFR(26) TFR(6)   x0 += k0;  x1 += k1 + 3u;
  TFR(17) TFR(29) TFR(16) TFR(24)  x0 += k1;  x1 += ks2 + 4u;
  TFR(13) TFR(15) TFR(26) TFR(6)   x0 += ks2; x1 += k0 + 5u;
#undef TFR
  y0 = x0; y1 = x1;
}

// Partitionable-mode 32-bit random bits for flat index idx (hi word of 64-bit iota == 0)
__device__ __forceinline__ unsigned tf_bits(unsigned k0, unsigned k1, unsigned idx){
  unsigned y0, y1; tf2x32_dev(k0, k1, 0u, idx, y0, y1); return y0 ^ y1;
}

__device__ __forceinline__ float u01_from_bits(unsigned bits){
  return __uint_as_float((bits >> 9) | 0x3f800000u) - 1.0f;
}

// XLA f32 ErfInv polynomial
__device__ __forceinline__ float erfinv_xla(float x){
  float w = -log1pf(-x*x);
  float p;
  if (w < 5.0f){
    w = w - 2.5f;
    p = 2.81022636e-08f;
    p = fmaf(p,w, 3.43273939e-07f);
    p = fmaf(p,w,-3.5233877e-06f);
    p = fmaf(p,w,-4.39150654e-06f);
    p = fmaf(p,w, 0.00021858087f);
    p = fmaf(p,w,-0.00125372503f);
    p = fmaf(p,w,-0.00417768164f);
    p = fmaf(p,w, 0.246640727f);
    p = fmaf(p,w, 1.50140941f);
  } else {
    w = sqrtf(w) - 3.0f;
    p = -0.000200214257f;
    p = fmaf(p,w, 0.000100950558f);
    p = fmaf(p,w, 0.00134934322f);
    p = fmaf(p,w,-0.00367342844f);
    p = fmaf(p,w, 0.00573950773f);
    p = fmaf(p,w,-0.0076224613f);
    p = fmaf(p,w, 0.00943887047f);
    p = fmaf(p,w, 1.00167406f);
    p = fmaf(p,w, 2.83297682f);
  }
  return p*x;
}

// ---------------- setup kernels ----------------
// Detect int64 vs int32 edge buffer: int64 => odd u32 words (high words) all zero.
__global__ void k_detect(const unsigned* __restrict__ raw, int* flag){
  unsigned v = raw[2*threadIdx.x + 1];
  unsigned long long m = __ballot(v == 0u);
  if (threadIdx.x == 0) *flag = (m == 0xFFFFFFFFFFFFFFFFull) ? 1 : 0;
}

__global__ void k_convert(const unsigned* __restrict__ raw, const int* __restrict__ flag,
                          int E, int* __restrict__ src, int* __restrict__ dst){
  int e = blockIdx.x*256 + threadIdx.x; if (e >= E) return;
  if (*flag){ src[e] = (int)raw[2*(size_t)e]; dst[e] = (int)raw[2*((size_t)E + e)]; }
  else      { const int* r = (const int*)raw; src[e] = r[e]; dst[e] = r[E + e]; }
}

__global__ void k_count(const int* __restrict__ dst, int E, int* __restrict__ cnt){
  int e = blockIdx.x*256 + threadIdx.x;
  if (e < E) atomicAdd(&cnt[dst[e]], 1);
}

// ---- fused per-block partial sums + degree histogram (one pass over cnt) ----
__global__ void k_psum_histo(const int* __restrict__ cnt, int N,
                             int* __restrict__ psum, int* __restrict__ bcnt){
  __shared__ int sh[256];
  __shared__ int lh[64];
  int tid = threadIdx.x; int n = blockIdx.x*256 + tid;
  int v = (n < N) ? cnt[n] : 0;
  sh[tid] = v;
  if (tid < 64) lh[tid] = 0;
  __syncthreads();
  if (n < N) atomicAdd(&lh[min(v, 63)], 1);
  for (int off = 128; off > 0; off >>= 1){
    __syncthreads();
    if (tid < off) sh[tid] += sh[tid + off];
  }
  __syncthreads();
  if (tid == 0) psum[blockIdx.x] = sh[0];
  if (tid < 64){
    int c = lh[tid];
    if (c > 0) atomicAdd(&bcnt[tid], c);
  }
}

// ---- fused single-block scans: exclusive scan of psum + descending-exclusive bcnt ----
__global__ void k_scan2(int* __restrict__ psum, int nb, int* __restrict__ bcnt){
  __shared__ int sh[256];
  __shared__ int sb[64];
  int tid = threadIdx.x;
  int v = (tid < nb) ? psum[tid] : 0;
  sh[tid] = v;
  if (tid < 64) sb[tid] = bcnt[tid];
  __syncthreads();
  for (int off = 1; off < 256; off <<= 1){
    int t = (tid >= off) ? sh[tid - off] : 0;
    __syncthreads();
    sh[tid] += t;
    __syncthreads();
  }
  if (tid < nb) psum[tid] = sh[tid] - v;   // exclusive
  if (tid < 64){                           // descending: high degree first
    int off = 0;
    for (int b2 = tid+1; b2 < 64; b2++) off += sb[b2];
    bcnt[tid] = off;
  }
}

// ---- fused rowptr/dis + degree-sorted permutation fill (one pass over cnt) ----
__global__ void k_rowptr_perm(const int* __restrict__ cnt, const int* __restrict__ psum,
                              int N, int E, int* __restrict__ rowptr, float* __restrict__ dis,
                              int* __restrict__ bcnt, int* __restrict__ perm){
  __shared__ int sh[256];
  __shared__ int lh[64];
  int tid = threadIdx.x; int n = blockIdx.x*256 + tid;
  int v = (n < N) ? cnt[n] : 0;
  sh[tid] = v;
  if (tid < 64) lh[tid] = 0;
  __syncthreads();
  int b = min(v, 63), r = 0;
  if (n < N) r = atomicAdd(&lh[b], 1);          // local rank within (block, bucket)
  for (int off = 1; off < 256; off <<= 1){
    int t = (tid >= off) ? sh[tid - off] : 0;
    __syncthreads();
    sh[tid] += t;
    __syncthreads();
  }
  if (n < N){
    rowptr[n] = psum[blockIdx.x] + sh[tid] - v;
    dis[n] = 1.0f / sqrtf((float)(v + 1));
  }
  if (n == N-1) rowptr[N] = E;
  if (tid < 64){
    int c = lh[tid];
    lh[tid] = (c > 0) ? atomicAdd(&bcnt[tid], c) : 0;   // reserve global range
  }
  __syncthreads();
  if (n < N) perm[lh[b] + r] = n;
}

__global__ void k_fill(const int* __restrict__ src, const int* __restrict__ dst, int E,
                       const int* __restrict__ rowptr, int* __restrict__ cnt,
                       const float* __restrict__ dis,
                       int* __restrict__ csr_src, float* __restrict__ csr_w){
  int e = blockIdx.x*256 + threadIdx.x; if (e >= E) return;
  int d = dst[e], s = src[e];
  int pos = atomicAdd(&cnt[d], 1);
  int slot = rowptr[d] + pos;
  csr_src[slot] = s;
  csr_w[slot] = dis[s]*dis[d];
}

// ---------------- h0 = x@proj_w + b, plus layer-0 quantization (delta=1) ----------------
__global__ __launch_bounds__(256) void k_h0(
  const float* __restrict__ x, const float* __restrict__ W, const float* __restrict__ bias,
  float* __restrict__ h0, float* __restrict__ hq, unsigned kq0, unsigned kq1, int N)
{
  __shared__ float xs[64*65];     // 64 nodes x 64 K-chunk, pad 65
  __shared__ float wsh[64*96];    // K-chunk x 96
  int tid = threadIdx.x; int n0 = blockIdx.x*64;
  int cg = tid & 15, ng = tid >> 4; int c0 = cg*6;
  float acc[4][6];
#pragma unroll
  for (int i=0;i<4;i++) for (int j=0;j<6;j++) acc[i][j]=0.f;
  for (int kc=0; kc<2; kc++){
    if (kc) __syncthreads();
    for (int q=tid; q<1536; q+=256)
      ((float4*)wsh)[q] = ((const float4*)(W + kc*64*96))[q];
    for (int q=tid; q<1024; q+=256){
      int g=q*4; int r=g>>6, col=g&63;
      int n=n0+r; int ns = n<N ? n : N-1;
      float4 v = ((const float4*)(x + (size_t)ns*128 + kc*64))[col>>2];
      xs[r*65+col]=v.x; xs[r*65+col+1]=v.y; xs[r*65+col+2]=v.z; xs[r*65+col+3]=v.w;
    }
    __syncthreads();
    for (int k=0;k<64;k++){
      float wv[6];
#pragma unroll
      for (int j=0;j<6;j++) wv[j]=wsh[k*96 + c0 + j];
#pragma unroll
      for (int i=0;i<4;i++){
        float xv = xs[(ng*4+i)*65 + k];
#pragma unroll
        for (int j=0;j<6;j++) acc[i][j] = fmaf(xv, wv[j], acc[i][j]);
      }
    }
  }
#pragma unroll
  for (int i=0;i<4;i++){
    int n = n0 + ng*4 + i; if (n >= N) continue;
#pragma unroll
    for (int j=0;j<6;j++){
      int c = c0 + j; int p = n*96 + c;
      float v = acc[i][j] + bias[c];
      h0[p] = v;
      unsigned bq = tf_bits(kq0, kq1, (unsigned)p);
      float b = u01_from_bits(bq) - 0.5f;     // delta = 1
      hq[p] = floorf(v + b) - b;
    }
  }
}

// ---------------- fused per-layer kernel ----------------
// Round 6: occupancy 3->4 blocks/CU. W staged in four 24-row chunks (9216 B) ->
// LDS = 25600 + 9216 + 256 = 35072 B. 16 waves/CU of gather MLP (was 12).
__global__ __launch_bounds__(256, 4) void k_layer(
  const float* __restrict__ hq_in, const float* __restrict__ h0, const float* __restrict__ dis,
  const int* __restrict__ rowptr, const int* __restrict__ csr_src, const float* __restrict__ csr_w,
  const int* __restrict__ perm, const float* __restrict__ W,
  float betaf, float ombf,
  unsigned ke0, unsigned ke1, unsigned kd0, unsigned kd1,
  unsigned kq0, unsigned kq1, float delta_n, float invdelta_n,
  int do_dropout, int write_h,
  float* __restrict__ hq_out, float* __restrict__ h_out, int N)
{
  __shared__ float ts[64*100];   // 25600 B t tile, stride 100
  __shared__ float wsh[24*96];   // 9216 B W K-chunk
  __shared__ int rowmap[64];     // node id per tile row
  int tid = threadIdx.x;
  int tx = tid & 31, ty = tid >> 5;    // 8 rows in flight
  int n0 = blockIdx.x*64;

  const float4* hq4 = (const float4*)hq_in;
  const float4* h04 = (const float4*)h0;

  // ---- phase 1: gather 64 rows, 8 passes of 8 concurrent rows ----
#pragma unroll 1
  for (int pass = 0; pass < 8; pass++){
    int r = pass*8 + ty;
    int row = n0 + r;
    int n = (row < N) ? perm[row] : -1;
    if (tx == 0) rowmap[r] = n;
    if (tx < 24){
      float4 o = make_float4(0.f, 0.f, 0.f, 0.f);
      if (n >= 0){
        float d = dis[n];
        int lo = rowptr[n], hi = rowptr[n+1];
        float4 self = hq4[(size_t)n*24 + tx];
        float dd = d*d;
        float ax = self.x*dd, ay = self.y*dd, az = self.z*dd, aw = self.w*dd;
        for (int s = lo; s < hi; s += 8){
          int   sn[8];
          float w[8];
#pragma unroll
          for (int j = 0; j < 8; j++){
            bool hv = (s + j) < hi;
            sn[j] = hv ? csr_src[s + j] : csr_src[s];
            w[j]  = hv ? csr_w[s + j]   : 0.0f;
          }
          float4 g[8];
#pragma unroll
          for (int j = 0; j < 8; j++) g[j] = hq4[(size_t)sn[j]*24 + tx];
#pragma unroll
          for (int j = 0; j < 8; j++){
            ax = fmaf(g[j].x, w[j], ax); ay = fmaf(g[j].y, w[j], ay);
            az = fmaf(g[j].z, w[j], az); aw = fmaf(g[j].w, w[j], aw);
          }
        }
        float4 hz = h04[(size_t)n*24 + tx];
        o.x = 0.9f*ax + 0.1f*hz.x;
        o.y = 0.9f*ay + 0.1f*hz.y;
        o.z = 0.9f*az + 0.1f*hz.z;
        o.w = 0.9f*aw + 0.1f*hz.w;
      }
      *((float4*)&ts[r*100 + tx*4]) = o;
    }
  }

  // ---- phase 2: matmul + epilogue ----
  int cg = tid & 7, ng = tid >> 3;   // cg 0..7, ng 0..31
  int c0 = cg * 12;
  int r0 = ng * 2;
  float acc[2][12];
#pragma unroll
  for (int i = 0; i < 2; i++)
#pragma unroll
    for (int j = 0; j < 12; j++) acc[i][j] = 0.f;

  for (int chunk = 0; chunk < 4; chunk++){
    __syncthreads();   // first: ts+rowmap staged; later: previous chunk consumed
    for (int q = tid; q < 576; q += 256)
      ((float4*)wsh)[q] = ((const float4*)(W + chunk*24*96))[q];
    __syncthreads();
#pragma unroll 4
    for (int kk = 0; kk < 24; kk++){
      int k = chunk*24 + kk;
      float4 w0 = *((const float4*)&wsh[kk*96 + c0]);
      float4 w1 = *((const float4*)&wsh[kk*96 + c0 + 4]);
      float4 w2 = *((const float4*)&wsh[kk*96 + c0 + 8]);
      float xv0 = ts[r0*100 + k];
      float xv1 = ts[(r0+1)*100 + k];
      acc[0][0] = fmaf(xv0, w0.x, acc[0][0]);  acc[0][1] = fmaf(xv0, w0.y, acc[0][1]);
      acc[0][2] = fmaf(xv0, w0.z, acc[0][2]);  acc[0][3] = fmaf(xv0, w0.w, acc[0][3]);
      acc[0][4] = fmaf(xv0, w1.x, acc[0][4]);  acc[0][5] = fmaf(xv0, w1.y, acc[0][5]);
      acc[0][6] = fmaf(xv0, w1.z, acc[0][6]);  acc[0][7] = fmaf(xv0, w1.w, acc[0][7]);
      acc[0][8] = fmaf(xv0, w2.x, acc[0][8]);  acc[0][9] = fmaf(xv0, w2.y, acc[0][9]);
      acc[0][10]= fmaf(xv0, w2.z, acc[0][10]); acc[0][11]= fmaf(xv0, w2.w, acc[0][11]);
      acc[1][0] = fmaf(xv1, w0.x, acc[1][0]);  acc[1][1] = fmaf(xv1, w0.y, acc[1][1]);
      acc[1][2] = fmaf(xv1, w0.z, acc[1][2]);  acc[1][3] = fmaf(xv1, w0.w, acc[1][3]);
      acc[1][4] = fmaf(xv1, w1.x, acc[1][4]);  acc[1][5] = fmaf(xv1, w1.y, acc[1][5]);
      acc[1][6] = fmaf(xv1, w1.z, acc[1][6]);  acc[1][7] = fmaf(xv1, w1.w, acc[1][7]);
      acc[1][8] = fmaf(xv1, w2.x, acc[1][8]);  acc[1][9] = fmaf(xv1, w2.y, acc[1][9]);
      acc[1][10]= fmaf(xv1, w2.z, acc[1][10]); acc[1][11]= fmaf(xv1, w2.w, acc[1][11]);
    }
  }

  const float LO = __uint_as_float(0xBF7FFFFFu);   // nextafter(-1,0)
#pragma unroll
  for (int i = 0; i < 2; i++){
    int n = rowmap[r0 + i]; if (n < 0) continue;
    float res[12];
#pragma unroll
    for (int j = 0; j < 12; j++){
      int c = c0 + j; int p = n*96 + c;
      float tv = ts[(r0+i)*100 + c];
      float hv = ombf*tv + betaf*acc[i][j];
      unsigned be = tf_bits(ke0, ke1, (unsigned)p);
      float uv = fmaxf(LO, u01_from_bits(be)*2.0f + LO);
      hv += 0.01f * (1.41421356f * erfinv_xla(uv));
      hv = fmaxf(hv, 0.0f);
      if (do_dropout){
        unsigned bd = tf_bits(kd0, kd1, (unsigned)p);
        hv = (bd < 0x80000000u) ? hv*2.0f : 0.0f;   // uniform<0.5 keep, /0.5
      }
      if (!write_h){
        unsigned bq = tf_bits(kq0, kq1, (unsigned)p);
        float b = (u01_from_bits(bq) - 0.5f)*delta_n;
        hv = floorf((hv + b)*invdelta_n)*delta_n - b;
      }
      res[j] = hv;
    }
    float* dst = (write_h ? h_out : hq_out) + (size_t)n*96 + c0;
#pragma unroll
    for (int j4 = 0; j4 < 3; j4++)
      *((float4*)&dst[j4*4]) = make_float4(res[j4*4], res[j4*4+1], res[j4*4+2], res[j4*4+3]);
  }
}

// ---------------- out = [h0, h] @ out_w + out_b ----------------
__global__ __launch_bounds__(256) void k_final(
  const float* __restrict__ h0, const float* __restrict__ h,
  const float* __restrict__ W, const float* __restrict__ bias,
  float* __restrict__ out, int N)
{
  __shared__ float xs[64*97];
  __shared__ float wsh[96*40];
  int tid = threadIdx.x; int n0 = blockIdx.x*64;
  int cg = tid & 7, ng = tid >> 3; int c0 = cg*5;
  float acc[2][5];
#pragma unroll
  for (int i=0;i<2;i++) for (int j=0;j<5;j++) acc[i][j]=0.f;
  for (int ph=0; ph<2; ph++){
    if (ph) __syncthreads();
    const float* xsrc = ph ? h : h0;
    for (int q=tid; q<960; q+=256)
      ((float4*)wsh)[q] = ((const float4*)(W + ph*96*40))[q];
    for (int q=tid; q<1536; q+=256){
      int g=q*4; int r=g/96, col=g%96;
      int n=n0+r; int ns = n<N ? n : N-1;
      float4 v = ((const float4*)(xsrc + (size_t)ns*96))[col>>2];
      xs[r*97+col]=v.x; xs[r*97+col+1]=v.y; xs[r*97+col+2]=v.z; xs[r*97+col+3]=v.w;
    }
    __syncthreads();
    for (int k=0;k<96;k++){
      float wv[5];
#pragma unroll
      for (int j=0;j<5;j++) wv[j]=wsh[k*40 + c0 + j];
#pragma unroll
      for (int i=0;i<2;i++){
        float xv = xs[(ng*2+i)*97 + k];
#pragma unroll
        for (int j=0;j<5;j++) acc[i][j] = fmaf(xv, wv[j], acc[i][j]);
      }
    }
  }
#pragma unroll
  for (int i=0;i<2;i++){
    int n = n0 + ng*2 + i; if (n >= N) continue;
#pragma unroll
    for (int j=0;j<5;j++)
      out[(size_t)n*40 + c0 + j] = acc[i][j] + bias[c0 + j];
  }
}

// ---------------- host ----------------
static void tf_host(uint32_t k0, uint32_t k1, uint32_t x0, uint32_t x1,
                    uint32_t &y0, uint32_t &y1){
  uint32_t ks2 = k0 ^ k1 ^ 0x1BD11BDAu;
  x0 += k0; x1 += k1;
  auto R = [&](int r){ x0 += x1; x1 = (x1<<r)|(x1>>(32-r)); x1 ^= x0; };
  R(13);R(15);R(26);R(6);   x0 += k1;  x1 += ks2 + 1u;
  R(17);R(29);R(16);R(24);  x0 += ks2; x1 += k0 + 2u;
  R(13);R(15);R(26);R(6);   x0 += k0;  x1 += k1 + 3u;
  R(17);R(29);R(16);R(24);  x0 += k1;  x1 += ks2 + 4u;
  R(13);R(15);R(26);R(6);   x0 += ks2; x1 += k0 + 5u;
  y0 = x0; y1 = x1;
}

extern "C" void kernel_launch(void* const* d_in, const int* in_sizes, int n_in,
                              void* d_out, int out_size, void* d_ws, size_t ws_size,
                              hipStream_t stream)
{
  const float*    x       = (const float*)d_in[0];
  const unsigned* eraw    = (const unsigned*)d_in[1];
  const float*    proj_w  = (const float*)d_in[2];
  const float*    proj_b  = (const float*)d_in[3];
  const float*    conv_w  = (const float*)d_in[4];
  const float*    out_w   = (const float*)d_in[5];
  const float*    out_b   = (const float*)d_in[6];
  float* out = (float*)d_out;

  const int N = in_sizes[0] / INC;     // 50000
  const int E = in_sizes[1] / 2;       // 800000
  const size_t NH = (size_t)N * HID;

  float* ws     = (float*)d_ws;
  float* h0     = ws;
  float* hq     = h0 + NH;       // ping
  float* tb     = hq + NH;       // pong
  float* hb     = tb + NH;
  float* dis    = hb + NH;
  int*   cnt    = (int*)(dis + N);
  int*   rowptr = cnt + N;
  int*   csr_src= rowptr + (N + 1);
  float* csr_w  = (float*)(csr_src + E);
  int*   srcb   = (int*)(csr_w + E);
  int*   dstb   = srcb + E;
  int*   flag   = dstb + E;
  int*   perm   = flag + 1;
  int*   bcnt   = perm + N;
  int*   psum   = bcnt + 64;
  (void)ws_size; (void)n_in; (void)out_size;

  // JAX key chain: key(42) -> per layer split(key,4) (partitionable foldlike)
  uint32_t kq[8][2], ke[8][2], kd[8][2];
  {
    uint32_t K0 = 0u, K1 = 42u;
    for (int k = 0; k < 8; k++){
      uint32_t y0, y1;
      tf_host(K0, K1, 0u, 0u, y0, y1); kq[k][0]=y0; kq[k][1]=y1;
      tf_host(K0, K1, 0u, 1u, y0, y1); ke[k][0]=y0; ke[k][1]=y1;
      tf_host(K0, K1, 0u, 2u, y0, y1); kd[k][0]=y0; kd[k][1]=y1;
      tf_host(K0, K1, 0u, 3u, y0, y1); K0=y0; K1=y1;
    }
  }

  const int gE  = (E + 255)/256;
  const int gN  = (N + 255)/256;   // partial-sum block count (196 <= 256)
  const int gMM = (N + 63)/64;

  hipMemsetAsync(cnt, 0, (size_t)N*4, stream);
  hipMemsetAsync(bcnt, 0, 64*4, stream);
  k_detect <<<1, 64, 0, stream>>>(eraw, flag);
  k_convert<<<gE, 256, 0, stream>>>(eraw, flag, E, srcb, dstb);
  k_count  <<<gE, 256, 0, stream>>>(dstb, E, cnt);
  k_psum_histo<<<gN, 256, 0, stream>>>(cnt, N, psum, bcnt);
  k_scan2  <<<1, 256, 0, stream>>>(psum, gN, bcnt);
  k_rowptr_perm<<<gN, 256, 0, stream>>>(cnt, psum, N, E, rowptr, dis, bcnt, perm);
  hipMemsetAsync(cnt, 0, (size_t)N*4, stream);
  k_fill   <<<gE, 256, 0, stream>>>(srcb, dstb, E, rowptr, cnt, dis, csr_src, csr_w);

  k_h0<<<gMM, 256, 0, stream>>>(x, proj_w, proj_b, h0, hq, kq[0][0], kq[0][1], N);

  for (int k = 0; k < 8; k++){
    double bd = log(0.5/(double)(k+1) + 1.0);
    float betaf = (float)bd;
    float ombf  = (float)(1.0 - bd);
    int last = (k == 7);
    float dn  = 1.0f/(float)(1 << (k+1));
    float idn = (float)(1 << (k+1));
    const float* hin  = (k & 1) ? tb : hq;   // ping-pong: no same-buffer read/write race
    float*       hout = (k & 1) ? hq : tb;
    k_layer<<<gMM, 256, 0, stream>>>(hin, h0, dis, rowptr, csr_src, csr_w, perm,
      conv_w + (size_t)k*HID*HID, betaf, ombf,
      ke[k][0], ke[k][1], kd[k][0], kd[k][1],
      last?0u:kq[k+1][0], last?0u:kq[k+1][1], dn, idn,
      !last, last, hout, hb, N);
  }

  k_final<<<gMM, 256, 0, stream>>>(h0, hb, out_w, out_b, out, N);
}